// Round 15
// baseline (248.264 us; speedup 1.0000x reference)
//
#include <hip/hip_runtime.h>
#include <hip/hip_bf16.h>
#include <math.h>

#define NB 2
#define NC 256
#define NZ 128
#define NHEADS 8
#define HDIM 64
#define HHID 512
#define EPSF 1e-5f

typedef __attribute__((ext_vector_type(8))) short bf16x8;
typedef __attribute__((ext_vector_type(4))) float f32x4;
typedef unsigned short ushort_t;

__device__ __forceinline__ float gelu_f(float x){
  const float u = 0.7978845608028654f * (x + 0.044715f * x * x * x);
  const float t = 1.0f - 2.0f / (__expf(2.0f * u) + 1.0f);  // tanh(u)
  return 0.5f * x * (1.0f + t);
}

__device__ __forceinline__ ushort_t f2bf(float x){
  unsigned int u = __float_as_uint(x);
  unsigned int r = ((u >> 16) & 1u) + 0x7fffu;   // round-to-nearest-even
  return (ushort_t)((u + r) >> 16);
}

__device__ __forceinline__ float bf2f(ushort_t u){
  return __uint_as_float(((unsigned int)u) << 16);
}

// sin(2*pi*t), cos(2*pi*t): v_sin/v_cos take REVOLUTIONS, fract-reduce first.
__device__ __forceinline__ void fsincos(float t, float* sn, float* cn){
  const float fr = t - floorf(t);
  *sn = __builtin_amdgcn_sinf(fr);
  *cn = __builtin_amdgcn_cosf(fr);
}

// ---------------- K0: pack weights + cm folds + per-(b,z) prep ----------------
// B-frag: idx=((s*T + t)*64 + L)*8 + j  <->  W[k=s*32+8*(L>>4)+j][n=16*t+(L&15)]
__global__ __launch_bounds__(256) void eca_pre(
    const float* __restrict__ mW1, const float* __restrict__ mW2, const float* __restrict__ vW2,
    const float* __restrict__ Wve, const float* __restrict__ vW1,
    const float* __restrict__ bve, const float* __restrict__ vb1,
    const float* __restrict__ a, const float* __restrict__ Wk, const float* __restrict__ bk,
    const float* __restrict__ Wv, const float* __restrict__ bv,
    const float* __restrict__ Wq, const float* __restrict__ bq,
    const float* __restrict__ Wqe, const float* __restrict__ bqe,
    const float* __restrict__ mg, const float* __restrict__ mbn, const float* __restrict__ mb2,
    ushort_t* __restrict__ W1p, ushort_t* __restrict__ W2p, ushort_t* __restrict__ vW2p,
    ushort_t* __restrict__ WveFp, float* __restrict__ bveF,
    float* __restrict__ cm1, float* __restrict__ cm2,
    ushort_t* __restrict__ v0t, float* __restrict__ kqf, float* __restrict__ bqkg)
{
  const int bx = blockIdx.x;
  const int tid = threadIdx.x;
  __shared__ float s_wf[64][64];
  __shared__ float s_a[64];
  __shared__ float s_k[512];
  __shared__ float s_kq[512];

  if (bx < 1024){
    const int i = bx * 256 + tid;
    {
      const int j = i & 7, L = (i >> 3) & 63, t = (i >> 9) & 31, s = i >> 14;
      const int k = s * 32 + ((L >> 4) << 3) + j;
      const int n = (t << 4) + (L & 15);
      W1p[i] = f2bf(mW1[k * 512 + n]);
      W2p[i] = f2bf(mW2[k * 512 + n]);
    }
    if (i < 65536){
      const int j = i & 7, L = (i >> 3) & 63, gb = (i >> 9) & 1, tp = (i >> 10) & 31, s = i >> 15;
      const int k = s * 32 + ((L >> 4) << 3) + j;
      const int n = (tp << 4) + (L & 15) + gb * 512;
      vW2p[i] = f2bf(vW2[k * 1024 + n]);
    }
    return;
  }
  if (bx == 1024){
    // fused front weight: WveF = Wve @ vW1 (64x64), bveF = bve@vW1 + vb1
    const int m = tid >> 2, iq = tid & 3;
    float accv[16];
    #pragma unroll
    for (int ii = 0; ii < 16; ++ii) accv[ii] = 0.f;
    for (int k = 0; k < 64; ++k){
      const float wv = Wve[m * 64 + k];
      const float4* vr = (const float4*)(vW1 + k * 64 + iq * 16);
      float t4[16];
      *(float4*)&t4[0] = vr[0]; *(float4*)&t4[4] = vr[1];
      *(float4*)&t4[8] = vr[2]; *(float4*)&t4[12] = vr[3];
      #pragma unroll
      for (int ii = 0; ii < 16; ++ii) accv[ii] += wv * t4[ii];
    }
    #pragma unroll
    for (int ii = 0; ii < 16; ++ii) s_wf[m][iq * 16 + ii] = accv[ii];
    if (tid < 64){
      float acc = vb1[tid];
      for (int k = 0; k < 64; ++k) acc += bve[k] * vW1[k * 64 + tid];
      bveF[tid] = acc;
    }
    __syncthreads();
    for (int e = tid; e < 4096; e += 256){
      const int j = e & 7, L = (e >> 3) & 63, t = (e >> 9) & 3, s = e >> 11;
      const int k = s * 32 + ((L >> 4) << 3) + j;
      const int n = (t << 4) + (L & 15);
      WveFp[e] = f2bf(s_wf[k][n]);
    }
    return;
  }
  if (bx == 1025){
    // cm1[n] = sum_k mg[k]*mW2[k,n]; cm2[n] = sum_k mbn[k]*mW2[k,n] + mb2[n]
    for (int nn = tid; nn < 512; nn += 256){
      float c1 = 0.f, c2 = 0.f;
      for (int k = 0; k < 512; ++k){
        const float w2 = mW2[k * 512 + nn];
        c1 += mg[k] * w2;
        c2 += mbn[k] * w2;
      }
      cm1[nn] = c1;
      cm2[nn] = c2 + mb2[nn];
    }
    return;
  }

  // ---- prep: bz = bx - 1026 ----
  const int bz = bx - 1026;
  const int bb = bz >> 7, zz = bz & 127;
  if (tid < 64) s_a[tid] = a[bz * 64 + tid];
  __syncthreads();
  #pragma unroll
  for (int jo = 0; jo < 2; ++jo){
    const int j = tid + jo * 256;
    float accK = bk[j], accV = bv[j];
    for (int i = 0; i < 64; ++i){
      const float av = s_a[i];
      accK += av * Wk[i * 512 + j];
      accV += av * Wv[i * 512 + j];
    }
    s_k[j] = accK;
    v0t[((size_t)bb * 512 + j) * 128 + zz] = f2bf(accV);   // transposed [b,n][z]
  }
  __syncthreads();
  #pragma unroll
  for (int io = 0; io < 2; ++io){
    const int idx = tid + io * 256;
    const int h = idx >> 6, i = idx & 63;
    float acc = 0.f;
    for (int j = 0; j < 64; ++j)
      acc += Wq[i * 512 + h * 64 + j] * s_k[h * 64 + j];
    s_kq[idx] = acc;
  }
  __syncthreads();
  // KqF[m,h]; layout kqf[bz*512 + (m>>4)*128 + h*16 + (m&15)]
  #pragma unroll
  for (int io = 0; io < 2; ++io){
    const int idx = tid + io * 256;
    const int m = idx >> 3, h = idx & 7;
    float acc = 0.f;
    for (int i = 0; i < 64; ++i) acc += Wqe[m * 64 + i] * s_kq[h * 64 + i];
    kqf[(size_t)bz * 512 + (m >> 4) * 128 + h * 16 + (m & 15)] = acc;
  }
  if (tid < 8){
    float acc = 0.f;
    for (int j = 0; j < 64; ++j) acc += bq[tid * 64 + j] * s_k[tid * 64 + j];
    for (int i = 0; i < 64; ++i) acc += bqe[i] * s_kq[tid * 64 + i];
    bqkg[bz * 8 + tid] = acc;
  }
}

// ---------------- K2: per-(b,c) logits+softmax+front -> attw + hn frags ----------------
__global__ __launch_bounds__(512, 8) void eca_front(
    const float* __restrict__ inputs, const float* __restrict__ p,
    const float* __restrict__ Bq, const float* __restrict__ Bv,
    const float* __restrict__ vg, const float* __restrict__ vbn,
    const float* __restrict__ kqf, const float* __restrict__ bqkg,
    const ushort_t* __restrict__ WveFp, const float* __restrict__ bveF,
    float* __restrict__ attw, ushort_t* __restrict__ hn_ws)
{
  const int bc = blockIdx.x;
  const int b = bc >> 8;
  const int tid = threadIdx.x;
  const int w = tid >> 6, L = tid & 63;
  const int al = L & 15, g = L >> 4;
  const int bz0 = b * NZ;

  __shared__ __align__(16) ushort_t s_HN[4096];  // 8KB hn frags (one pass)
  __shared__ float s_att[1024];
  __shared__ float s_u[512];
  __shared__ float s_qpt[3];

  if (tid < 3) s_qpt[tid] = inputs[bc * 3 + tid];
  __syncthreads();

  // ---------- logits: thread (z = tid>>2, q = tid&3); two 4-head groups ----------
  {
    const int z = tid >> 2, q = tid & 3;
    const float iv0 = s_qpt[0] - p[(bz0 + z) * 3 + 0];
    const float iv1 = s_qpt[1] - p[(bz0 + z) * 3 + 1];
    const float iv2 = s_qpt[2] - p[(bz0 + z) * 3 + 2];
    float tr[16];
    #pragma unroll
    for (int mi = 0; mi < 16; ++mi){
      const int mb = (q & 1) * 16 + mi;
      const float d = iv0 * Bq[mb] + iv1 * Bq[32 + mb] + iv2 * Bq[64 + mb];
      float sn, cn; fsincos(d, &sn, &cn);
      tr[mi] = (q < 2) ? sn : cn;
    }
    const float* kfb = kqf + (size_t)(bz0 + z) * 512 + q * 128;
    #pragma unroll 1
    for (int hg = 0; hg < 2; ++hg){
      float lg[4];
      #pragma unroll
      for (int h4 = 0; h4 < 4; ++h4){
        const int h = hg * 4 + h4;
        const float4 k0 = *(const float4*)(kfb + h * 16);
        const float4 k1 = *(const float4*)(kfb + h * 16 + 4);
        const float4 k2 = *(const float4*)(kfb + h * 16 + 8);
        const float4 k3 = *(const float4*)(kfb + h * 16 + 12);
        lg[h4] = tr[0]*k0.x + tr[1]*k0.y + tr[2]*k0.z + tr[3]*k0.w
               + tr[4]*k1.x + tr[5]*k1.y + tr[6]*k1.z + tr[7]*k1.w
               + tr[8]*k2.x + tr[9]*k2.y + tr[10]*k2.z + tr[11]*k2.w
               + tr[12]*k3.x + tr[13]*k3.y + tr[14]*k3.z + tr[15]*k3.w;
      }
      #pragma unroll
      for (int h4 = 0; h4 < 4; ++h4){
        lg[h4] += __shfl_xor(lg[h4], 1);
        lg[h4] += __shfl_xor(lg[h4], 2);
      }
      const int h = hg * 4 + q;
      s_att[h * 128 + z] = (lg[q] + bqkg[(bz0 + z) * 8 + h]) * 0.125f;
    }
  }
  __syncthreads();

  // ---------- softmax over z (head w per wave) -> attw ----------
  {
    const float x0 = s_att[w * 128 + L], x1 = s_att[w * 128 + L + 64];
    float mx = fmaxf(x0, x1);
    #pragma unroll
    for (int off = 32; off; off >>= 1) mx = fmaxf(mx, __shfl_xor(mx, off));
    const float e0 = __expf(x0 - mx), e1 = __expf(x1 - mx);
    float sm = e0 + e1;
    #pragma unroll
    for (int off = 32; off; off >>= 1) sm += __shfl_xor(sm, off);
    const float inv = 1.f / sm;
    attw[(size_t)bc * 1024 + w * 128 + L]      = e0 * inv;
    attw[(size_t)bc * 1024 + w * 128 + L + 64] = e1 * inv;
  }

  const int rtf = w & 3, ch2 = w >> 2;

  #pragma unroll 1
  for (int pass = 0; pass < 2; ++pass){
    const int zp = pass * 64;
    __syncthreads();                                   // protect s_u / s_HN reuse

    // ---------- front: hn = LN64(gelu(f @ WveF + bveF)) ----------
    {
      const int zz = bz0 + zp + rtf * 16 + al;
      const float iv0 = s_qpt[0] - p[zz * 3 + 0];
      const float iv1 = s_qpt[1] - p[zz * 3 + 1];
      const float iv2 = s_qpt[2] - p[zz * 3 + 2];
      bf16x8 fa0, fa1;
      #pragma unroll
      for (int j = 0; j < 8; ++j){
        const int m = g * 8 + j;
        const float d = iv0 * Bv[m] + iv1 * Bv[32 + m] + iv2 * Bv[64 + m];
        float sn, cn; fsincos(d, &sn, &cn);
        fa0[j] = (short)f2bf(sn);
        fa1[j] = (short)f2bf(cn);
      }
      f32x4 accf[2] = {{0,0,0,0},{0,0,0,0}};
      #pragma unroll
      for (int ct = 0; ct < 2; ++ct){
        const int t = ch2 * 2 + ct;
        const bf16x8 b0 = *(const bf16x8*)(WveFp + ((0 * 4 + t) * 64 + L) * 8);
        const bf16x8 b1 = *(const bf16x8*)(WveFp + ((1 * 4 + t) * 64 + L) * 8);
        accf[ct] = __builtin_amdgcn_mfma_f32_16x16x32_bf16(fa0, b0, accf[ct], 0, 0, 0);
        accf[ct] = __builtin_amdgcn_mfma_f32_16x16x32_bf16(fa1, b1, accf[ct], 0, 0, 0);
      }
      float h1v[2][4];
      #pragma unroll
      for (int r = 0; r < 4; ++r){
        float sv = 0.f, qv = 0.f;
        #pragma unroll
        for (int ct = 0; ct < 2; ++ct){
          const float v = gelu_f(accf[ct][r] + bveF[ch2 * 32 + ct * 16 + al]);
          h1v[ct][r] = v; sv += v; qv += v * v;
        }
        sv += __shfl_xor(sv, 1); sv += __shfl_xor(sv, 2);
        sv += __shfl_xor(sv, 4); sv += __shfl_xor(sv, 8);
        qv += __shfl_xor(qv, 1); qv += __shfl_xor(qv, 2);
        qv += __shfl_xor(qv, 4); qv += __shfl_xor(qv, 8);
        if (al == 0){
          const int row = rtf * 16 + 4 * g + r;
          s_u[row * 4 + ch2 * 2 + 0] = sv;
          s_u[row * 4 + ch2 * 2 + 1] = qv;
        }
      }
      __syncthreads();
      #pragma unroll
      for (int r = 0; r < 4; ++r){
        const int row = rtf * 16 + 4 * g + r;
        const float sv = s_u[row * 4 + 0] + s_u[row * 4 + 2];
        const float qv = s_u[row * 4 + 1] + s_u[row * 4 + 3];
        const float mu = sv * (1.f / 64.f);
        const float rs = rsqrtf(qv * (1.f / 64.f) - mu * mu + EPSF);
        #pragma unroll
        for (int ct = 0; ct < 2; ++ct){
          const int n = ch2 * 32 + ct * 16 + al;
          const float val = (h1v[ct][r] - mu) * rs * vg[n] + vbn[n];
          s_HN[((n >> 5) * 4 + rtf) * 512 + ((4 * g + r) + 16 * ((n >> 3) & 3)) * 8 + (n & 7)] = f2bf(val);
        }
      }
    }
    __syncthreads();
    // copy hn frags to ws (linear, vectorized)
    ((uint4*)(hn_ws + (size_t)bc * 8192 + pass * 4096))[tid] = ((const uint4*)s_HN)[tid];
  }
}

// ---------------- K3: per-(b,c) gb + GEMM1 + A' via MFMA (slim arch-VGPR peaks) ----------------
// A_ws[h][bc][k] (f32) = sum_z att[h,z]*rs[z]*h2[z,k]; S1_ws[bc][h] = sum_z att*mu*rs
__global__ __launch_bounds__(512, 4) void eca_gemm(
    const ushort_t* __restrict__ hn_ws, const float* __restrict__ attw,
    const ushort_t* __restrict__ v0t,
    const float* __restrict__ vb2, const float* __restrict__ mb1,
    const ushort_t* __restrict__ W1p, const ushort_t* __restrict__ vW2p,
    float* __restrict__ A_ws, float* __restrict__ S1_ws)
{
  const int bc = blockIdx.x;
  const int b = bc >> 8;
  const int tid = threadIdx.x;
  const int w = tid >> 6, L = tid & 63;
  const int al = L & 15, g = L >> 4;

  __shared__ __align__(16) ushort_t s_A[16 * 4 * 64 * 8];   // 64KB
  __shared__ __align__(16) ushort_t s_HN[4096];             // 8KB
  __shared__ float s_att[1024];
  __shared__ float s_u[512];
  __shared__ float s_rs[32];
  __shared__ float s_rsmu[128];

  s_att[tid] = attw[(size_t)bc * 1024 + tid];
  s_att[tid + 512] = attw[(size_t)bc * 1024 + 512 + tid];

  f32x4 accA[4];
  #pragma unroll
  for (int ct = 0; ct < 4; ++ct) accA[ct] = (f32x4){0.f, 0.f, 0.f, 0.f};

  #pragma unroll 1
  for (int pass = 0; pass < 2; ++pass){
    const int zp = pass * 64;
    __syncthreads();
    // stage hn frags (8KB)
    {
      const uint4 v = ((const uint4*)(hn_ws + (size_t)bc * 8192 + pass * 4096))[tid];
      ((uint4*)s_HN)[tid] = v;
    }
    __syncthreads();

    // ---------- gb MFMA: per-rt epilogue-inline; v0 via transposed ushort4 loads ----------
    #pragma unroll 1
    for (int it = 0; it < 4; ++it){
      const int tp = w * 4 + it;
      const int n = tp * 16 + al;
      const float gbias = vb2[n], bbias = vb2[512 + n];
      #pragma unroll 1
      for (int rt = 0; rt < 4; ++rt){
        f32x4 accg = {0,0,0,0}, accb = {0,0,0,0};
        #pragma unroll
        for (int s = 0; s < 2; ++s){
          const bf16x8 bg = *(const bf16x8*)(vW2p + (size_t)(((s * 32 + tp) * 2 + 0) * 64 + L) * 8);
          const bf16x8 bb = *(const bf16x8*)(vW2p + (size_t)(((s * 32 + tp) * 2 + 1) * 64 + L) * 8);
          const bf16x8 af = *(const bf16x8*)(s_HN + ((s * 4 + rt) * 64 + L) * 8);
          accg = __builtin_amdgcn_mfma_f32_16x16x32_bf16(af, bg, accg, 0, 0, 0);
          accb = __builtin_amdgcn_mfma_f32_16x16x32_bf16(af, bb, accb, 0, 0, 0);
        }
        const ushort4 vv = *(const ushort4*)(v0t + ((size_t)b * 512 + n) * 128 + zp + rt * 16 + 4 * g);
        #pragma unroll
        for (int r = 0; r < 4; ++r){
          const ushort_t vu = (r == 0) ? vv.x : ((r == 1) ? vv.y : ((r == 2) ? vv.z : vv.w));
          const float vf = bf2f(vu) * (1.f + accg[r] + gbias) + (accb[r] + bbias);
          s_A[((n >> 5) * 4 + rt) * 512 + ((4 * g + r) + 16 * ((n >> 3) & 3)) * 8 + (n & 7)] = f2bf(vf);
        }
      }
    }
    __syncthreads();

    // ---------- GEMM1 (two 32-z chunks, ct-split halves): h2; stats via LDS; A' via MFMA ----------
    #pragma unroll 1
    for (int rc = 0; rc < 2; ++rc){
      // half A: ct 0,1
      f32x4 accP[2][2];
      #pragma unroll
      for (int i = 0; i < 2; ++i){ accP[i][0] = (f32x4){0,0,0,0}; accP[i][1] = (f32x4){0,0,0,0}; }
      #pragma unroll 1
      for (int s = 0; s < 16; ++s){
        bf16x8 bw0 = *(const bf16x8*)(W1p + (size_t)((s * 32 + w * 4 + 0) * 64 + L) * 8);
        bf16x8 bw1 = *(const bf16x8*)(W1p + (size_t)((s * 32 + w * 4 + 1) * 64 + L) * 8);
        const bf16x8 a0 = *(const bf16x8*)(s_A + ((s * 4 + rc * 2 + 0) * 64 + L) * 8);
        const bf16x8 a1 = *(const bf16x8*)(s_A + ((s * 4 + rc * 2 + 1) * 64 + L) * 8);
        accP[0][0] = __builtin_amdgcn_mfma_f32_16x16x32_bf16(a0, bw0, accP[0][0], 0, 0, 0);
        accP[0][1] = __builtin_amdgcn_mfma_f32_16x16x32_bf16(a0, bw1, accP[0][1], 0, 0, 0);
        accP[1][0] = __builtin_amdgcn_mfma_f32_16x16x32_bf16(a1, bw0, accP[1][0], 0, 0, 0);
        accP[1][1] = __builtin_amdgcn_mfma_f32_16x16x32_bf16(a1, bw1, accP[1][1], 0, 0, 0);
      }
      // gelu half A + stats partials -> s_u
      #pragma unroll
      for (int i = 0; i < 2; ++i){
        #pragma unroll
        for (int r = 0; r < 4; ++r){
          float sv = 0.f, qv = 0.f;
          #pragma unroll
          for (int ct = 0; ct < 2; ++ct){
            const float v = gelu_f(accP[i][ct][r] + mb1[w * 64 + ct * 16 + al]);
            accP[i][ct][r] = v; sv += v; qv += v * v;
          }
          sv += __shfl_xor(sv, 1); sv += __shfl_xor(sv, 2);
          sv += __shfl_xor(sv, 4); sv += __shfl_xor(sv, 8);
          qv += __shfl_xor(qv, 1); qv += __shfl_xor(qv, 2);
          qv += __shfl_xor(qv, 4); qv += __shfl_xor(qv, 8);
          if (al == 0){
            const int zloc = i * 16 + 4 * g + r;
            s_u[zloc * 16 + w * 2 + 0] = sv;
            s_u[zloc * 16 + w * 2 + 1] = qv;
          }
        }
      }
      // half B: ct 2,3
      f32x4 accQ[2][2];
      #pragma unroll
      for (int i = 0; i < 2; ++i){ accQ[i][0] = (f32x4){0,0,0,0}; accQ[i][1] = (f32x4){0,0,0,0}; }
      #pragma unroll 1
      for (int s = 0; s < 16; ++s){
        bf16x8 bw0 = *(const bf16x8*)(W1p + (size_t)((s * 32 + w * 4 + 2) * 64 + L) * 8);
        bf16x8 bw1 = *(const bf16x8*)(W1p + (size_t)((s * 32 + w * 4 + 3) * 64 + L) * 8);
        const bf16x8 a0 = *(const bf16x8*)(s_A + ((s * 4 + rc * 2 + 0) * 64 + L) * 8);
        const bf16x8 a1 = *(const bf16x8*)(s_A + ((s * 4 + rc * 2 + 1) * 64 + L) * 8);
        accQ[0][0] = __builtin_amdgcn_mfma_f32_16x16x32_bf16(a0, bw0, accQ[0][0], 0, 0, 0);
        accQ[0][1] = __builtin_amdgcn_mfma_f32_16x16x32_bf16(a0, bw1, accQ[0][1], 0, 0, 0);
        accQ[1][0] = __builtin_amdgcn_mfma_f32_16x16x32_bf16(a1, bw0, accQ[1][0], 0, 0, 0);
        accQ[1][1] = __builtin_amdgcn_mfma_f32_16x16x32_bf16(a1, bw1, accQ[1][1], 0, 0, 0);
      }
      // gelu half B + stats add into s_u (single writer lane per row)
      #pragma unroll
      for (int i = 0; i < 2; ++i){
        #pragma unroll
        for (int r = 0; r < 4; ++r){
          float sv = 0.f, qv = 0.f;
          #pragma unroll
          for (int ct = 0; ct < 2; ++ct){
            const float v = gelu_f(accQ[i][ct][r] + mb1[w * 64 + (ct + 2) * 16 + al]);
            accQ[i][ct][r] = v; sv += v; qv += v * v;
          }
          sv += __shfl_xor(sv, 1); sv += __shfl_xor(sv, 2);
          sv += __shfl_xor(sv, 4); sv += __shfl_xor(sv, 8);
          qv += __shfl_xor(qv, 1); qv += __shfl_xor(qv, 2);
          qv += __shfl_xor(qv, 4); qv += __shfl_xor(qv, 8);
          if (al == 0){
            const int zloc = i * 16 + 4 * g + r;
            s_u[zloc * 16 + w * 2 + 0] += sv;
            s_u[zloc * 16 + w * 2 + 1] += qv;
          }
        }
      }
      __syncthreads();                 // waves done reading chunk's A-frags + partials visible
      if (tid < 32){
        float sv = 0.f, qv = 0.f;
        #pragma unroll
        for (int ww = 0; ww < 8; ++ww){ sv += s_u[tid * 16 + ww * 2]; qv += s_u[tid * 16 + ww * 2 + 1]; }
        const float mu = sv * (1.f / 512.f);
        const float rs = rsqrtf(qv * (1.f / 512.f) - mu * mu + EPSF);
        s_rs[tid] = rs;
        s_rsmu[zp + rc * 32 + tid] = mu * rs;
      }
      __syncthreads();
      // write h2*rs as B-frags (K=z) into this chunk's now-dead s_A slots
      #pragma unroll
      for (int i = 0; i < 2; ++i){
        #pragma unroll
        for (int r = 0; r < 4; ++r){
          const int zr = i * 16 + 4 * g + r;         // chunk-local z 0..31
          const float rsv = s_rs[zr];
          #pragma unroll
          for (int ct = 0; ct < 4; ++ct){
            const int sl = 2 * w + (ct >> 1);
            const int rt = rc * 2 + (ct & 1);
            const float hv = (ct < 2) ? accP[i][ct][r] : accQ[i][ct - 2][r];
            s_A[((sl * 4 + rt) * 64 + (zr >> 3) * 16 + al) * 8 + (zr & 7)] = f2bf(hv * rsv);
          }
        }
      }
      __syncthreads();
      // A' MFMA: accA[ct] += att_frag @ (rs*h2)_frag  (K = 32 z of this chunk)
      {
        const int chunk = pass * 2 + rc;
        bf16x8 fa;
        if (al < 8){
          const float* ar = s_att + al * 128 + chunk * 32 + g * 8;
          #pragma unroll
          for (int j = 0; j < 8; ++j) fa[j] = (short)f2bf(ar[j]);
        } else {
          #pragma unroll
          for (int j = 0; j < 8; ++j) fa[j] = 0;
        }
        #pragma unroll
        for (int ct = 0; ct < 4; ++ct){
          const int sl = 2 * w + (ct >> 1);
          const int rt = rc * 2 + (ct & 1);
          const bf16x8 bb = *(const bf16x8*)(s_A + ((sl * 4 + rt) * 64 + L) * 8);
          accA[ct] = __builtin_amdgcn_mfma_f32_16x16x32_bf16(fa, bb, accA[ct], 0, 0, 0);
        }
      }
    }
  }

  // ---------- S1[h] = sum_z att[h,z]*rsmu[z] (wave w -> head w) ----------
  __syncthreads();
  {
    float sS = s_att[w * 128 + L] * s_rsmu[L] + s_att[w * 128 + L + 64] * s_rsmu[L + 64];
    #pragma unroll
    for (int off = 32; off; off >>= 1) sS += __shfl_xor(sS, off);
    if (L == 0) S1_ws[bc * 8 + w] = sS;
  }

  // ---------- write A' (f32): lane rows h = g*4+r valid for g<2 ----------
  if (g < 2){
    #pragma unroll
    for (int ct = 0; ct < 4; ++ct){
      #pragma unroll
      for (int r = 0; r < 4; ++r){
        const int h = g * 4 + r;
        A_ws[((size_t)h * 512 + bc) * 512 + w * 64 + ct * 16 + al] = accA[ct][r];
      }
    }
  }
}

// ---------------- K4: y[c,n] = (mg*A'[h(n),c,:]) @ mW2[:,n] - S1[c,h]*cm1[n] + cm2[n] ----------------
__global__ __launch_bounds__(256) void eca_y(
    const float* __restrict__ A_ws, const ushort_t* __restrict__ W2p,
    const float* __restrict__ S1_ws,
    const float* __restrict__ cm1, const float* __restrict__ cm2,
    const float* __restrict__ mg,
    float* __restrict__ yws)
{
  const int bx = blockIdx.x;
  const int h = bx >> 5, ctile = bx & 31;
  const int c0 = ctile * 16;
  const int tid = threadIdx.x;
  const int w = tid >> 6, L = tid & 63;
  const int al = L & 15, g = L >> 4;
  __shared__ float s_S1[16];
  if (tid < 16) s_S1[tid] = S1_ws[(c0 + tid) * 8 + h];
  __syncthreads();
  f32x4 acc = {0.f, 0.f, 0.f, 0.f};
  const int t = h * 4 + w;
  const float* Arow = A_ws + ((size_t)h * 512 + c0 + al) * 512;
  #pragma unroll 1
  for (int s = 0; s < 16; ++s){
    const int k0 = s * 32 + g * 8;
    const float4 a0 = *(const float4*)(Arow + k0);
    const float4 a1 = *(const float4*)(Arow + k0 + 4);
    const float4 m0 = *(const float4*)(mg + k0);
    const float4 m1 = *(const float4*)(mg + k0 + 4);
    bf16x8 a;
    a[0] = (short)f2bf(a0.x * m0.x); a[1] = (short)f2bf(a0.y * m0.y);
    a[2] = (short)f2bf(a0.z * m0.z); a[3] = (short)f2bf(a0.w * m0.w);
    a[4] = (short)f2bf(a1.x * m1.x); a[5] = (short)f2bf(a1.y * m1.y);
    a[6] = (short)f2bf(a1.z * m1.z); a[7] = (short)f2bf(a1.w * m1.w);
    const bf16x8 bw = *(const bf16x8*)(W2p + (size_t)((s * 32 + t) * 64 + L) * 8);
    acc = __builtin_amdgcn_mfma_f32_16x16x32_bf16(a, bw, acc, 0, 0, 0);
  }
  const int n = h * 64 + w * 16 + al;
  const float c1 = cm1[n], c2 = cm2[n];
  #pragma unroll
  for (int r = 0; r < 4; ++r){
    const int c = c0 + 4 * g + r;
    yws[(size_t)c * 512 + n] = acc[r] - s_S1[4 * g + r] * c1 + c2;
  }
}

// ---------------- K5: out = y @ Wo + bo (f32) ----------------
__global__ __launch_bounds__(256) void eca_out(
    const float* __restrict__ y, const float* __restrict__ Wo, const float* __restrict__ bo,
    float* __restrict__ out)
{
  const int rt = blockIdx.x >> 2, ct = blockIdx.x & 3;    // 32 row-tiles x 4 col-tiles
  const int tid = threadIdx.x;
  __shared__ float s_y[16][512];
  const float* yb = y + (size_t)rt * 16 * 512;
  for (int i = tid; i < 16 * 128; i += 256)
    ((float4*)&s_y[0][0])[i] = ((const float4*)yb)[i];
  __syncthreads();
  const int jc = ct * 128 + (tid & 31) * 4;
  const int r0 = (tid >> 5) * 2;
  float acc[2][4] = {};
  #pragma unroll 4
  for (int k = 0; k < 512; ++k){
    const float4 wv = *(const float4*)(Wo + (size_t)k * 512 + jc);
    #pragma unroll
    for (int r = 0; r < 2; ++r){
      const float yvv = s_y[r0 + r][k];
      acc[r][0] += yvv * wv.x; acc[r][1] += yvv * wv.y;
      acc[r][2] += yvv * wv.z; acc[r][3] += yvv * wv.w;
    }
  }
  const float4 bv4 = *(const float4*)(bo + jc);
  #pragma unroll
  for (int r = 0; r < 2; ++r){
    float4 o;
    o.x = acc[r][0] + bv4.x; o.y = acc[r][1] + bv4.y;
    o.z = acc[r][2] + bv4.z; o.w = acc[r][3] + bv4.w;
    *(float4*)(out + (size_t)(rt * 16 + r0 + r) * 512 + jc) = o;
  }
}

extern "C" void kernel_launch(void* const* d_in, const int* in_sizes, int n_in,
                              void* d_out, int out_size, void* d_ws, size_t ws_size,
                              hipStream_t stream)
{
  const float* inputs = (const float*)d_in[0];
  const float* p   = (const float*)d_in[1];
  const float* a   = (const float*)d_in[2];
  const float* Bq  = (const float*)d_in[3];
  const float* Wqe = (const float*)d_in[4];
  const float* bqe = (const float*)d_in[5];
  const float* Bv  = (const float*)d_in[6];
  const float* Wve = (const float*)d_in[7];
  const float* bve = (const float*)d_in[8];
  const float* Wq  = (const float*)d_in[9];
  const float* bq  = (const float*)d_in[10];
  const float* Wk  = (const float*)d_in[11];
  const float* bk  = (const float*)d_in[12];
  const float* Wv  = (const float*)d_in[13];
  const float* bv  = (const float*)d_in[14];
  const float* vW1 = (const float*)d_in[15];
  const float* vb1 = (const float*)d_in[16];
  const float* vg  = (const float*)d_in[17];
  const float* vbn = (const float*)d_in[18];
  const float* vW2 = (const float*)d_in[19];
  const float* vb2 = (const float*)d_in[20];
  const float* mW1 = (const float*)d_in[21];
  const float* mb1 = (const float*)d_in[22];
  const float* mg  = (const float*)d_in[23];
  const float* mbn = (const float*)d_in[24];
  const float* mW2 = (const float*)d_in[25];
  const float* mb2 = (const float*)d_in[26];
  const float* Wo  = (const float*)d_in[27];
  const float* bo  = (const float*)d_in[28];
  (void)in_sizes; (void)n_in; (void)out_size; (void)ws_size;

  float* kqf  = (float*)d_ws;                        // 131072 f32
  float* bqkg = kqf + 131072;                        // 2048 f32
  float* yws  = bqkg + 2048;                         // 262144 f32
  float* cm1  = yws + 262144;                        // 512 f32
  float* cm2  = cm1 + 512;                           // 512 f32
  float* S1w  = cm2 + 512;                           // 4096 f32
  float* attw = S1w + 4096;                          // 524288 f32 (2 MB)
  float* A_ws = attw + 524288;                       // 2097152 f32 (8 MB)
  float* bveF = A_ws + 2097152;                      // 64 f32
  ushort_t* W1p   = (ushort_t*)(bveF + 64);          // 262144 bf16
  ushort_t* W2p   = W1p + 262144;                    // 262144 bf16
  ushort_t* vW2p  = W2p + 262144;                    // 65536 bf16
  ushort_t* WveFp = vW2p + 65536;                    // 4096 bf16
  ushort_t* v0t   = WveFp + 4096;                    // 131072 bf16 (transposed [b,n][z])
  ushort_t* hn_ws = v0t + 131072;                    // 4194304 bf16 (8 MB)
  float* out = (float*)d_out;

  eca_pre<<<dim3(1282), dim3(256), 0, stream>>>(
      mW1, mW2, vW2, Wve, vW1, bve, vb1,
      a, Wk, bk, Wv, bv, Wq, bq, Wqe, bqe,
      mg, mbn, mb2,
      W1p, W2p, vW2p, WveFp, bveF, cm1, cm2, v0t, kqf, bqkg);
  eca_front<<<dim3(NB * NC), dim3(512), 0, stream>>>(
      inputs, p, Bq, Bv, vg, vbn, kqf, bqkg, WveFp, bveF, attw, hn_ws);
  eca_gemm<<<dim3(NB * NC), dim3(512), 0, stream>>>(
      hn_ws, attw, v0t, vb2, mb1, W1p, vW2p, A_ws, S1w);
  eca_y<<<dim3(256), dim3(256), 0, stream>>>(A_ws, W2p, S1w, cm1, cm2, mg, yws);
  eca_out<<<dim3(128), dim3(256), 0, stream>>>(yws, Wo, bo, out);
}

// Round 16
// 217.438 us; speedup vs baseline: 1.1418x; 1.1418x over previous
//
#include <hip/hip_runtime.h>
#include <hip/hip_bf16.h>
#include <math.h>

#define NB 2
#define NC 256
#define NZ 128
#define NHEADS 8
#define HDIM 64
#define HHID 512
#define EPSF 1e-5f

typedef __attribute__((ext_vector_type(8))) short bf16x8;
typedef __attribute__((ext_vector_type(4))) float f32x4;
typedef unsigned short ushort_t;

__device__ __forceinline__ float gelu_f(float x){
  const float u = 0.7978845608028654f * (x + 0.044715f * x * x * x);
  const float t = 1.0f - 2.0f / (__expf(2.0f * u) + 1.0f);  // tanh(u)
  return 0.5f * x * (1.0f + t);
}

__device__ __forceinline__ ushort_t f2bf(float x){
  unsigned int u = __float_as_uint(x);
  unsigned int r = ((u >> 16) & 1u) + 0x7fffu;   // round-to-nearest-even
  return (ushort_t)((u + r) >> 16);
}

__device__ __forceinline__ float bf2f(ushort_t u){
  return __uint_as_float(((unsigned int)u) << 16);
}

// sin(2*pi*t), cos(2*pi*t): v_sin/v_cos take REVOLUTIONS, fract-reduce first.
__device__ __forceinline__ void fsincos(float t, float* sn, float* cn){
  const float fr = t - floorf(t);
  *sn = __builtin_amdgcn_sinf(fr);
  *cn = __builtin_amdgcn_cosf(fr);
}

// ---------------- K0: pack weights + cm folds + per-(b,z) prep ----------------
// B-frag: idx=((s*T + t)*64 + L)*8 + j  <->  W[k=s*32+8*(L>>4)+j][n=16*t+(L&15)]
__global__ __launch_bounds__(256) void eca_pre(
    const float* __restrict__ mW1, const float* __restrict__ mW2, const float* __restrict__ vW2,
    const float* __restrict__ Wve, const float* __restrict__ vW1,
    const float* __restrict__ bve, const float* __restrict__ vb1,
    const float* __restrict__ a, const float* __restrict__ Wk, const float* __restrict__ bk,
    const float* __restrict__ Wv, const float* __restrict__ bv,
    const float* __restrict__ Wq, const float* __restrict__ bq,
    const float* __restrict__ Wqe, const float* __restrict__ bqe,
    const float* __restrict__ mg, const float* __restrict__ mbn, const float* __restrict__ mb2,
    ushort_t* __restrict__ W1p, ushort_t* __restrict__ W2p, ushort_t* __restrict__ vW2p,
    ushort_t* __restrict__ WveFp, float* __restrict__ bveF,
    float* __restrict__ cm1, float* __restrict__ cm2,
    ushort_t* __restrict__ v0gh, float* __restrict__ kqf, float* __restrict__ bqkg)
{
  const int bx = blockIdx.x;
  const int tid = threadIdx.x;
  __shared__ float s_wf[64][64];
  __shared__ float s_a[64];
  __shared__ float s_k[512];
  __shared__ float s_kq[512];

  if (bx < 1024){
    const int i = bx * 256 + tid;
    {
      const int j = i & 7, L = (i >> 3) & 63, t = (i >> 9) & 31, s = i >> 14;
      const int k = s * 32 + ((L >> 4) << 3) + j;
      const int n = (t << 4) + (L & 15);
      W1p[i] = f2bf(mW1[k * 512 + n]);
      W2p[i] = f2bf(mW2[k * 512 + n]);
    }
    if (i < 65536){
      const int j = i & 7, L = (i >> 3) & 63, gb = (i >> 9) & 1, tp = (i >> 10) & 31, s = i >> 15;
      const int k = s * 32 + ((L >> 4) << 3) + j;
      const int n = (tp << 4) + (L & 15) + gb * 512;
      vW2p[i] = f2bf(vW2[k * 1024 + n]);
    }
    return;
  }
  if (bx == 1024){
    // fused front weight: WveF = Wve @ vW1 (64x64), bveF = bve@vW1 + vb1
    const int m = tid >> 2, iq = tid & 3;
    float accv[16];
    #pragma unroll
    for (int ii = 0; ii < 16; ++ii) accv[ii] = 0.f;
    for (int k = 0; k < 64; ++k){
      const float wv = Wve[m * 64 + k];
      const float4* vr = (const float4*)(vW1 + k * 64 + iq * 16);
      float t4[16];
      *(float4*)&t4[0] = vr[0]; *(float4*)&t4[4] = vr[1];
      *(float4*)&t4[8] = vr[2]; *(float4*)&t4[12] = vr[3];
      #pragma unroll
      for (int ii = 0; ii < 16; ++ii) accv[ii] += wv * t4[ii];
    }
    #pragma unroll
    for (int ii = 0; ii < 16; ++ii) s_wf[m][iq * 16 + ii] = accv[ii];
    if (tid < 64){
      float acc = vb1[tid];
      for (int k = 0; k < 64; ++k) acc += bve[k] * vW1[k * 64 + tid];
      bveF[tid] = acc;
    }
    __syncthreads();
    for (int e = tid; e < 4096; e += 256){
      const int j = e & 7, L = (e >> 3) & 63, t = (e >> 9) & 3, s = e >> 11;
      const int k = s * 32 + ((L >> 4) << 3) + j;
      const int n = (t << 4) + (L & 15);
      WveFp[e] = f2bf(s_wf[k][n]);
    }
    return;
  }
  if (bx == 1025){
    // cm1[n] = sum_k mg[k]*mW2[k,n]; cm2[n] = sum_k mbn[k]*mW2[k,n] + mb2[n]
    for (int nn = tid; nn < 512; nn += 256){
      float c1 = 0.f, c2 = 0.f;
      for (int k = 0; k < 512; ++k){
        const float w2 = mW2[k * 512 + nn];
        c1 += mg[k] * w2;
        c2 += mbn[k] * w2;
      }
      cm1[nn] = c1;
      cm2[nn] = c2 + mb2[nn];
    }
    return;
  }

  // ---- prep: bz = bx - 1026 ----
  const int bz = bx - 1026;
  if (tid < 64) s_a[tid] = a[bz * 64 + tid];
  __syncthreads();
  #pragma unroll
  for (int jo = 0; jo < 2; ++jo){
    const int j = tid + jo * 256;
    float accK = bk[j], accV = bv[j];
    for (int i = 0; i < 64; ++i){
      const float av = s_a[i];
      accK += av * Wk[i * 512 + j];
      accV += av * Wv[i * 512 + j];
    }
    s_k[j] = accK;
    v0gh[(size_t)bz * 512 + j] = f2bf(accV);
  }
  __syncthreads();
  #pragma unroll
  for (int io = 0; io < 2; ++io){
    const int idx = tid + io * 256;
    const int h = idx >> 6, i = idx & 63;
    float acc = 0.f;
    for (int j = 0; j < 64; ++j)
      acc += Wq[i * 512 + h * 64 + j] * s_k[h * 64 + j];
    s_kq[idx] = acc;
  }
  __syncthreads();
  // KqF[m,h]; layout kqf[bz*512 + (m>>4)*128 + h*16 + (m&15)]
  #pragma unroll
  for (int io = 0; io < 2; ++io){
    const int idx = tid + io * 256;
    const int m = idx >> 3, h = idx & 7;
    float acc = 0.f;
    for (int i = 0; i < 64; ++i) acc += Wqe[m * 64 + i] * s_kq[h * 64 + i];
    kqf[(size_t)bz * 512 + (m >> 4) * 128 + h * 16 + (m & 15)] = acc;
  }
  if (tid < 8){
    float acc = 0.f;
    for (int j = 0; j < 64; ++j) acc += bq[tid * 64 + j] * s_k[tid * 64 + j];
    for (int i = 0; i < 64; ++i) acc += bqe[i] * s_kq[tid * 64 + i];
    bqkg[bz * 8 + tid] = acc;
  }
}

// ---------------- K2: per-(b,c) logits+softmax+front -> attw + hn frags ----------------
__global__ __launch_bounds__(512, 4) void eca_front(
    const float* __restrict__ inputs, const float* __restrict__ p,
    const float* __restrict__ Bq, const float* __restrict__ Bv,
    const float* __restrict__ vg, const float* __restrict__ vbn,
    const float* __restrict__ kqf, const float* __restrict__ bqkg,
    const ushort_t* __restrict__ WveFp, const float* __restrict__ bveF,
    float* __restrict__ attw, ushort_t* __restrict__ hn_ws)
{
  const int bc = blockIdx.x;
  const int b = bc >> 8;
  const int tid = threadIdx.x;
  const int w = tid >> 6, L = tid & 63;
  const int al = L & 15, g = L >> 4;
  const int bz0 = b * NZ;

  __shared__ __align__(16) ushort_t s_HN[4096];  // 8KB hn frags (one pass)
  __shared__ float s_att[1024];
  __shared__ float s_u[512];
  __shared__ float s_qpt[3];

  if (tid < 3) s_qpt[tid] = inputs[bc * 3 + tid];
  __syncthreads();

  // ---------- logits: thread (z = tid>>2, q = tid&3); two 4-head groups ----------
  {
    const int z = tid >> 2, q = tid & 3;
    const float iv0 = s_qpt[0] - p[(bz0 + z) * 3 + 0];
    const float iv1 = s_qpt[1] - p[(bz0 + z) * 3 + 1];
    const float iv2 = s_qpt[2] - p[(bz0 + z) * 3 + 2];
    float tr[16];
    #pragma unroll
    for (int mi = 0; mi < 16; ++mi){
      const int mb = (q & 1) * 16 + mi;
      const float d = iv0 * Bq[mb] + iv1 * Bq[32 + mb] + iv2 * Bq[64 + mb];
      float sn, cn; fsincos(d, &sn, &cn);
      tr[mi] = (q < 2) ? sn : cn;
    }
    const float* kfb = kqf + (size_t)(bz0 + z) * 512 + q * 128;
    #pragma unroll 1
    for (int hg = 0; hg < 2; ++hg){
      float lg[4];
      #pragma unroll
      for (int h4 = 0; h4 < 4; ++h4){
        const int h = hg * 4 + h4;
        const float4 k0 = *(const float4*)(kfb + h * 16);
        const float4 k1 = *(const float4*)(kfb + h * 16 + 4);
        const float4 k2 = *(const float4*)(kfb + h * 16 + 8);
        const float4 k3 = *(const float4*)(kfb + h * 16 + 12);
        lg[h4] = tr[0]*k0.x + tr[1]*k0.y + tr[2]*k0.z + tr[3]*k0.w
               + tr[4]*k1.x + tr[5]*k1.y + tr[6]*k1.z + tr[7]*k1.w
               + tr[8]*k2.x + tr[9]*k2.y + tr[10]*k2.z + tr[11]*k2.w
               + tr[12]*k3.x + tr[13]*k3.y + tr[14]*k3.z + tr[15]*k3.w;
      }
      #pragma unroll
      for (int h4 = 0; h4 < 4; ++h4){
        lg[h4] += __shfl_xor(lg[h4], 1);
        lg[h4] += __shfl_xor(lg[h4], 2);
      }
      const int h = hg * 4 + q;
      s_att[h * 128 + z] = (lg[q] + bqkg[(bz0 + z) * 8 + h]) * 0.125f;
    }
  }
  __syncthreads();

  // ---------- softmax over z (head w per wave) -> attw ----------
  {
    const float x0 = s_att[w * 128 + L], x1 = s_att[w * 128 + L + 64];
    float mx = fmaxf(x0, x1);
    #pragma unroll
    for (int off = 32; off; off >>= 1) mx = fmaxf(mx, __shfl_xor(mx, off));
    const float e0 = __expf(x0 - mx), e1 = __expf(x1 - mx);
    float sm = e0 + e1;
    #pragma unroll
    for (int off = 32; off; off >>= 1) sm += __shfl_xor(sm, off);
    const float inv = 1.f / sm;
    attw[(size_t)bc * 1024 + w * 128 + L]      = e0 * inv;
    attw[(size_t)bc * 1024 + w * 128 + L + 64] = e1 * inv;
  }

  const int rtf = w & 3, ch2 = w >> 2;

  #pragma unroll 1
  for (int pass = 0; pass < 2; ++pass){
    const int zp = pass * 64;
    __syncthreads();                                   // protect s_u / s_HN reuse

    // ---------- front: hn = LN64(gelu(f @ WveF + bveF)) ----------
    {
      const int zz = bz0 + zp + rtf * 16 + al;
      const float iv0 = s_qpt[0] - p[zz * 3 + 0];
      const float iv1 = s_qpt[1] - p[zz * 3 + 1];
      const float iv2 = s_qpt[2] - p[zz * 3 + 2];
      bf16x8 fa0, fa1;
      #pragma unroll
      for (int j = 0; j < 8; ++j){
        const int m = g * 8 + j;
        const float d = iv0 * Bv[m] + iv1 * Bv[32 + m] + iv2 * Bv[64 + m];
        float sn, cn; fsincos(d, &sn, &cn);
        fa0[j] = (short)f2bf(sn);
        fa1[j] = (short)f2bf(cn);
      }
      f32x4 accf[2] = {{0,0,0,0},{0,0,0,0}};
      #pragma unroll
      for (int ct = 0; ct < 2; ++ct){
        const int t = ch2 * 2 + ct;
        const bf16x8 b0 = *(const bf16x8*)(WveFp + ((0 * 4 + t) * 64 + L) * 8);
        const bf16x8 b1 = *(const bf16x8*)(WveFp + ((1 * 4 + t) * 64 + L) * 8);
        accf[ct] = __builtin_amdgcn_mfma_f32_16x16x32_bf16(fa0, b0, accf[ct], 0, 0, 0);
        accf[ct] = __builtin_amdgcn_mfma_f32_16x16x32_bf16(fa1, b1, accf[ct], 0, 0, 0);
      }
      float h1v[2][4];
      #pragma unroll
      for (int r = 0; r < 4; ++r){
        float sv = 0.f, qv = 0.f;
        #pragma unroll
        for (int ct = 0; ct < 2; ++ct){
          const float v = gelu_f(accf[ct][r] + bveF[ch2 * 32 + ct * 16 + al]);
          h1v[ct][r] = v; sv += v; qv += v * v;
        }
        sv += __shfl_xor(sv, 1); sv += __shfl_xor(sv, 2);
        sv += __shfl_xor(sv, 4); sv += __shfl_xor(sv, 8);
        qv += __shfl_xor(qv, 1); qv += __shfl_xor(qv, 2);
        qv += __shfl_xor(qv, 4); qv += __shfl_xor(qv, 8);
        if (al == 0){
          const int row = rtf * 16 + 4 * g + r;
          s_u[row * 4 + ch2 * 2 + 0] = sv;
          s_u[row * 4 + ch2 * 2 + 1] = qv;
        }
      }
      __syncthreads();
      #pragma unroll
      for (int r = 0; r < 4; ++r){
        const int row = rtf * 16 + 4 * g + r;
        const float sv = s_u[row * 4 + 0] + s_u[row * 4 + 2];
        const float qv = s_u[row * 4 + 1] + s_u[row * 4 + 3];
        const float mu = sv * (1.f / 64.f);
        const float rs = rsqrtf(qv * (1.f / 64.f) - mu * mu + EPSF);
        #pragma unroll
        for (int ct = 0; ct < 2; ++ct){
          const int n = ch2 * 32 + ct * 16 + al;
          const float val = (h1v[ct][r] - mu) * rs * vg[n] + vbn[n];
          s_HN[((n >> 5) * 4 + rtf) * 512 + ((4 * g + r) + 16 * ((n >> 3) & 3)) * 8 + (n & 7)] = f2bf(val);
        }
      }
    }
    __syncthreads();
    // copy hn frags to ws (linear, vectorized)
    ((uint4*)(hn_ws + (size_t)bc * 8192 + pass * 4096))[tid] = ((const uint4*)s_HN)[tid];
  }
}

// ---------------- K3: per-(b,c) gb + GEMM1 + A' via MFMA (slim arch-VGPR peaks) ----------------
// A_ws[h][bc][k] (f32) = sum_z att[h,z]*rs[z]*h2[z,k]; S1_ws[bc][h] = sum_z att*mu*rs
__global__ __launch_bounds__(512, 4) void eca_gemm(
    const ushort_t* __restrict__ hn_ws, const float* __restrict__ attw,
    const ushort_t* __restrict__ v0gh,
    const float* __restrict__ vb2, const float* __restrict__ mb1,
    const ushort_t* __restrict__ W1p, const ushort_t* __restrict__ vW2p,
    float* __restrict__ A_ws, float* __restrict__ S1_ws)
{
  const int bc = blockIdx.x;
  const int b = bc >> 8;
  const int tid = threadIdx.x;
  const int w = tid >> 6, L = tid & 63;
  const int al = L & 15, g = L >> 4;
  const int bz0 = b * NZ;

  __shared__ __align__(16) ushort_t s_A[16 * 4 * 64 * 8];   // 64KB
  __shared__ __align__(16) ushort_t s_HN[4096];             // 8KB
  __shared__ float s_att[1024];
  __shared__ float s_u[512];
  __shared__ float s_rs[32];
  __shared__ float s_rsmu[128];

  s_att[tid] = attw[(size_t)bc * 1024 + tid];
  s_att[tid + 512] = attw[(size_t)bc * 1024 + 512 + tid];

  f32x4 accA[4];
  #pragma unroll
  for (int ct = 0; ct < 4; ++ct) accA[ct] = (f32x4){0.f, 0.f, 0.f, 0.f};

  #pragma unroll 1
  for (int pass = 0; pass < 2; ++pass){
    const int zp = pass * 64;
    __syncthreads();
    // stage hn frags (8KB)
    {
      const uint4 v = ((const uint4*)(hn_ws + (size_t)bc * 8192 + pass * 4096))[tid];
      ((uint4*)s_HN)[tid] = v;
    }
    __syncthreads();

    // ---------- gb MFMA: per-rt epilogue-inline (low arch live; vW2p re-read per rt) ----------
    #pragma unroll 1
    for (int it = 0; it < 4; ++it){
      const int tp = w * 4 + it;
      const int n = tp * 16 + al;
      const float gbias = vb2[n], bbias = vb2[512 + n];
      #pragma unroll 1
      for (int rt = 0; rt < 4; ++rt){
        f32x4 accg = {0,0,0,0}, accb = {0,0,0,0};
        #pragma unroll
        for (int s = 0; s < 2; ++s){
          const bf16x8 bg = *(const bf16x8*)(vW2p + (size_t)(((s * 32 + tp) * 2 + 0) * 64 + L) * 8);
          const bf16x8 bb = *(const bf16x8*)(vW2p + (size_t)(((s * 32 + tp) * 2 + 1) * 64 + L) * 8);
          const bf16x8 af = *(const bf16x8*)(s_HN + ((s * 4 + rt) * 64 + L) * 8);
          accg = __builtin_amdgcn_mfma_f32_16x16x32_bf16(af, bg, accg, 0, 0, 0);
          accb = __builtin_amdgcn_mfma_f32_16x16x32_bf16(af, bb, accb, 0, 0, 0);
        }
        #pragma unroll
        for (int r = 0; r < 4; ++r){
          const int zl = rt * 16 + 4 * g + r;
          const float v0v = bf2f(v0gh[(size_t)(bz0 + zp + zl) * 512 + n]);
          const float vf = v0v * (1.f + accg[r] + gbias) + (accb[r] + bbias);
          s_A[((n >> 5) * 4 + rt) * 512 + ((4 * g + r) + 16 * ((n >> 3) & 3)) * 8 + (n & 7)] = f2bf(vf);
        }
      }
    }
    __syncthreads();

    // ---------- GEMM1 (two 32-z chunks, ct-split halves): h2; stats via LDS; A' via MFMA ----------
    #pragma unroll 1
    for (int rc = 0; rc < 2; ++rc){
      // half A: ct 0,1
      f32x4 accP[2][2];
      #pragma unroll
      for (int i = 0; i < 2; ++i){ accP[i][0] = (f32x4){0,0,0,0}; accP[i][1] = (f32x4){0,0,0,0}; }
      #pragma unroll 1
      for (int s = 0; s < 16; ++s){
        bf16x8 bw0 = *(const bf16x8*)(W1p + (size_t)((s * 32 + w * 4 + 0) * 64 + L) * 8);
        bf16x8 bw1 = *(const bf16x8*)(W1p + (size_t)((s * 32 + w * 4 + 1) * 64 + L) * 8);
        const bf16x8 a0 = *(const bf16x8*)(s_A + ((s * 4 + rc * 2 + 0) * 64 + L) * 8);
        const bf16x8 a1 = *(const bf16x8*)(s_A + ((s * 4 + rc * 2 + 1) * 64 + L) * 8);
        accP[0][0] = __builtin_amdgcn_mfma_f32_16x16x32_bf16(a0, bw0, accP[0][0], 0, 0, 0);
        accP[0][1] = __builtin_amdgcn_mfma_f32_16x16x32_bf16(a0, bw1, accP[0][1], 0, 0, 0);
        accP[1][0] = __builtin_amdgcn_mfma_f32_16x16x32_bf16(a1, bw0, accP[1][0], 0, 0, 0);
        accP[1][1] = __builtin_amdgcn_mfma_f32_16x16x32_bf16(a1, bw1, accP[1][1], 0, 0, 0);
      }
      // gelu half A + stats partials -> s_u
      #pragma unroll
      for (int i = 0; i < 2; ++i){
        #pragma unroll
        for (int r = 0; r < 4; ++r){
          float sv = 0.f, qv = 0.f;
          #pragma unroll
          for (int ct = 0; ct < 2; ++ct){
            const float v = gelu_f(accP[i][ct][r] + mb1[w * 64 + ct * 16 + al]);
            accP[i][ct][r] = v; sv += v; qv += v * v;
          }
          sv += __shfl_xor(sv, 1); sv += __shfl_xor(sv, 2);
          sv += __shfl_xor(sv, 4); sv += __shfl_xor(sv, 8);
          qv += __shfl_xor(qv, 1); qv += __shfl_xor(qv, 2);
          qv += __shfl_xor(qv, 4); qv += __shfl_xor(qv, 8);
          if (al == 0){
            const int zloc = i * 16 + 4 * g + r;
            s_u[zloc * 16 + w * 2 + 0] = sv;
            s_u[zloc * 16 + w * 2 + 1] = qv;
          }
        }
      }
      // half B: ct 2,3
      f32x4 accQ[2][2];
      #pragma unroll
      for (int i = 0; i < 2; ++i){ accQ[i][0] = (f32x4){0,0,0,0}; accQ[i][1] = (f32x4){0,0,0,0}; }
      #pragma unroll 1
      for (int s = 0; s < 16; ++s){
        bf16x8 bw0 = *(const bf16x8*)(W1p + (size_t)((s * 32 + w * 4 + 2) * 64 + L) * 8);
        bf16x8 bw1 = *(const bf16x8*)(W1p + (size_t)((s * 32 + w * 4 + 3) * 64 + L) * 8);
        const bf16x8 a0 = *(const bf16x8*)(s_A + ((s * 4 + rc * 2 + 0) * 64 + L) * 8);
        const bf16x8 a1 = *(const bf16x8*)(s_A + ((s * 4 + rc * 2 + 1) * 64 + L) * 8);
        accQ[0][0] = __builtin_amdgcn_mfma_f32_16x16x32_bf16(a0, bw0, accQ[0][0], 0, 0, 0);
        accQ[0][1] = __builtin_amdgcn_mfma_f32_16x16x32_bf16(a0, bw1, accQ[0][1], 0, 0, 0);
        accQ[1][0] = __builtin_amdgcn_mfma_f32_16x16x32_bf16(a1, bw0, accQ[1][0], 0, 0, 0);
        accQ[1][1] = __builtin_amdgcn_mfma_f32_16x16x32_bf16(a1, bw1, accQ[1][1], 0, 0, 0);
      }
      // gelu half B + stats add into s_u (single writer lane per row)
      #pragma unroll
      for (int i = 0; i < 2; ++i){
        #pragma unroll
        for (int r = 0; r < 4; ++r){
          float sv = 0.f, qv = 0.f;
          #pragma unroll
          for (int ct = 0; ct < 2; ++ct){
            const float v = gelu_f(accQ[i][ct][r] + mb1[w * 64 + (ct + 2) * 16 + al]);
            accQ[i][ct][r] = v; sv += v; qv += v * v;
          }
          sv += __shfl_xor(sv, 1); sv += __shfl_xor(sv, 2);
          sv += __shfl_xor(sv, 4); sv += __shfl_xor(sv, 8);
          qv += __shfl_xor(qv, 1); qv += __shfl_xor(qv, 2);
          qv += __shfl_xor(qv, 4); qv += __shfl_xor(qv, 8);
          if (al == 0){
            const int zloc = i * 16 + 4 * g + r;
            s_u[zloc * 16 + w * 2 + 0] += sv;
            s_u[zloc * 16 + w * 2 + 1] += qv;
          }
        }
      }
      __syncthreads();                 // waves done reading chunk's A-frags + partials visible
      if (tid < 32){
        float sv = 0.f, qv = 0.f;
        #pragma unroll
        for (int ww = 0; ww < 8; ++ww){ sv += s_u[tid * 16 + ww * 2]; qv += s_u[tid * 16 + ww * 2 + 1]; }
        const float mu = sv * (1.f / 512.f);
        const float rs = rsqrtf(qv * (1.f / 512.f) - mu * mu + EPSF);
        s_rs[tid] = rs;
        s_rsmu[zp + rc * 32 + tid] = mu * rs;
      }
      __syncthreads();
      // write h2*rs as B-frags (K=z) into this chunk's now-dead s_A slots
      #pragma unroll
      for (int i = 0; i < 2; ++i){
        #pragma unroll
        for (int r = 0; r < 4; ++r){
          const int zr = i * 16 + 4 * g + r;         // chunk-local z 0..31
          const float rsv = s_rs[zr];
          #pragma unroll
          for (int ct = 0; ct < 4; ++ct){
            const int sl = 2 * w + (ct >> 1);
            const int rt = rc * 2 + (ct & 1);
            const float hv = (ct < 2) ? accP[i][ct][r] : accQ[i][ct - 2][r];
            s_A[((sl * 4 + rt) * 64 + (zr >> 3) * 16 + al) * 8 + (zr & 7)] = f2bf(hv * rsv);
          }
        }
      }
      __syncthreads();
      // A' MFMA: accA[ct] += att_frag @ (rs*h2)_frag  (K = 32 z of this chunk)
      {
        const int chunk = pass * 2 + rc;
        bf16x8 fa;
        if (al < 8){
          const float* ar = s_att + al * 128 + chunk * 32 + g * 8;
          #pragma unroll
          for (int j = 0; j < 8; ++j) fa[j] = (short)f2bf(ar[j]);
        } else {
          #pragma unroll
          for (int j = 0; j < 8; ++j) fa[j] = 0;
        }
        #pragma unroll
        for (int ct = 0; ct < 4; ++ct){
          const int sl = 2 * w + (ct >> 1);
          const int rt = rc * 2 + (ct & 1);
          const bf16x8 bb = *(const bf16x8*)(s_A + ((sl * 4 + rt) * 64 + L) * 8);
          accA[ct] = __builtin_amdgcn_mfma_f32_16x16x32_bf16(fa, bb, accA[ct], 0, 0, 0);
        }
      }
    }
  }

  // ---------- S1[h] = sum_z att[h,z]*rsmu[z] (wave w -> head w) ----------
  __syncthreads();
  {
    float sS = s_att[w * 128 + L] * s_rsmu[L] + s_att[w * 128 + L + 64] * s_rsmu[L + 64];
    #pragma unroll
    for (int off = 32; off; off >>= 1) sS += __shfl_xor(sS, off);
    if (L == 0) S1_ws[bc * 8 + w] = sS;
  }

  // ---------- write A' (f32): lane rows h = g*4+r valid for g<2 ----------
  if (g < 2){
    #pragma unroll
    for (int ct = 0; ct < 4; ++ct){
      #pragma unroll
      for (int r = 0; r < 4; ++r){
        const int h = g * 4 + r;
        A_ws[((size_t)h * 512 + bc) * 512 + w * 64 + ct * 16 + al] = accA[ct][r];
      }
    }
  }
}

// ---------------- K4: y[c,n] = (mg*A'[h(n),c,:]) @ mW2[:,n] - S1[c,h]*cm1[n] + cm2[n] ----------------
__global__ __launch_bounds__(256) void eca_y(
    const float* __restrict__ A_ws, const ushort_t* __restrict__ W2p,
    const float* __restrict__ S1_ws,
    const float* __restrict__ cm1, const float* __restrict__ cm2,
    const float* __restrict__ mg,
    float* __restrict__ yws)
{
  const int bx = blockIdx.x;
  const int h = bx >> 5, ctile = bx & 31;
  const int c0 = ctile * 16;
  const int tid = threadIdx.x;
  const int w = tid >> 6, L = tid & 63;
  const int al = L & 15, g = L >> 4;
  __shared__ float s_S1[16];
  if (tid < 16) s_S1[tid] = S1_ws[(c0 + tid) * 8 + h];
  __syncthreads();
  f32x4 acc = {0.f, 0.f, 0.f, 0.f};
  const int t = h * 4 + w;
  const float* Arow = A_ws + ((size_t)h * 512 + c0 + al) * 512;
  #pragma unroll 1
  for (int s = 0; s < 16; ++s){
    const int k0 = s * 32 + g * 8;
    const float4 a0 = *(const float4*)(Arow + k0);
    const float4 a1 = *(const float4*)(Arow + k0 + 4);
    const float4 m0 = *(const float4*)(mg + k0);
    const float4 m1 = *(const float4*)(mg + k0 + 4);
    bf16x8 a;
    a[0] = (short)f2bf(a0.x * m0.x); a[1] = (short)f2bf(a0.y * m0.y);
    a[2] = (short)f2bf(a0.z * m0.z); a[3] = (short)f2bf(a0.w * m0.w);
    a[4] = (short)f2bf(a1.x * m1.x); a[5] = (short)f2bf(a1.y * m1.y);
    a[6] = (short)f2bf(a1.z * m1.z); a[7] = (short)f2bf(a1.w * m1.w);
    const bf16x8 bw = *(const bf16x8*)(W2p + (size_t)((s * 32 + t) * 64 + L) * 8);
    acc = __builtin_amdgcn_mfma_f32_16x16x32_bf16(a, bw, acc, 0, 0, 0);
  }
  const int n = h * 64 + w * 16 + al;
  const float c1 = cm1[n], c2 = cm2[n];
  #pragma unroll
  for (int r = 0; r < 4; ++r){
    const int c = c0 + 4 * g + r;
    yws[(size_t)c * 512 + n] = acc[r] - s_S1[4 * g + r] * c1 + c2;
  }
}

// ---------------- K5: out = y @ Wo + bo (f32) ----------------
__global__ __launch_bounds__(256) void eca_out(
    const float* __restrict__ y, const float* __restrict__ Wo, const float* __restrict__ bo,
    float* __restrict__ out)
{
  const int rt = blockIdx.x >> 2, ct = blockIdx.x & 3;    // 32 row-tiles x 4 col-tiles
  const int tid = threadIdx.x;
  __shared__ float s_y[16][512];
  const float* yb = y + (size_t)rt * 16 * 512;
  for (int i = tid; i < 16 * 128; i += 256)
    ((float4*)&s_y[0][0])[i] = ((const float4*)yb)[i];
  __syncthreads();
  const int jc = ct * 128 + (tid & 31) * 4;
  const int r0 = (tid >> 5) * 2;
  float acc[2][4] = {};
  #pragma unroll 4
  for (int k = 0; k < 512; ++k){
    const float4 wv = *(const float4*)(Wo + (size_t)k * 512 + jc);
    #pragma unroll
    for (int r = 0; r < 2; ++r){
      const float yvv = s_y[r0 + r][k];
      acc[r][0] += yvv * wv.x; acc[r][1] += yvv * wv.y;
      acc[r][2] += yvv * wv.z; acc[r][3] += yvv * wv.w;
    }
  }
  const float4 bv4 = *(const float4*)(bo + jc);
  #pragma unroll
  for (int r = 0; r < 2; ++r){
    float4 o;
    o.x = acc[r][0] + bv4.x; o.y = acc[r][1] + bv4.y;
    o.z = acc[r][2] + bv4.z; o.w = acc[r][3] + bv4.w;
    *(float4*)(out + (size_t)(rt * 16 + r0 + r) * 512 + jc) = o;
  }
}

extern "C" void kernel_launch(void* const* d_in, const int* in_sizes, int n_in,
                              void* d_out, int out_size, void* d_ws, size_t ws_size,
                              hipStream_t stream)
{
  const float* inputs = (const float*)d_in[0];
  const float* p   = (const float*)d_in[1];
  const float* a   = (const float*)d_in[2];
  const float* Bq  = (const float*)d_in[3];
  const float* Wqe = (const float*)d_in[4];
  const float* bqe = (const float*)d_in[5];
  const float* Bv  = (const float*)d_in[6];
  const float* Wve = (const float*)d_in[7];
  const float* bve = (const float*)d_in[8];
  const float* Wq  = (const float*)d_in[9];
  const float* bq  = (const float*)d_in[10];
  const float* Wk  = (const float*)d_in[11];
  const float* bk  = (const float*)d_in[12];
  const float* Wv  = (const float*)d_in[13];
  const float* bv  = (const float*)d_in[14];
  const float* vW1 = (const float*)d_in[15];
  const float* vb1 = (const float*)d_in[16];
  const float* vg  = (const float*)d_in[17];
  const float* vbn = (const float*)d_in[18];
  const float* vW2 = (const float*)d_in[19];
  const float* vb2 = (const float*)d_in[20];
  const float* mW1 = (const float*)d_in[21];
  const float* mb1 = (const float*)d_in[22];
  const float* mg  = (const float*)d_in[23];
  const float* mbn = (const float*)d_in[24];
  const float* mW2 = (const float*)d_in[25];
  const float* mb2 = (const float*)d_in[26];
  const float* Wo  = (const float*)d_in[27];
  const float* bo  = (const float*)d_in[28];
  (void)in_sizes; (void)n_in; (void)out_size; (void)ws_size;

  float* kqf  = (float*)d_ws;                        // 131072 f32
  float* bqkg = kqf + 131072;                        // 2048 f32
  float* yws  = bqkg + 2048;                         // 262144 f32
  float* cm1  = yws + 262144;                        // 512 f32
  float* cm2  = cm1 + 512;                           // 512 f32
  float* S1w  = cm2 + 512;                           // 4096 f32
  float* attw = S1w + 4096;                          // 524288 f32 (2 MB)
  float* A_ws = attw + 524288;                       // 2097152 f32 (8 MB)
  float* bveF = A_ws + 2097152;                      // 64 f32
  ushort_t* W1p   = (ushort_t*)(bveF + 64);          // 262144 bf16
  ushort_t* W2p   = W1p + 262144;                    // 262144 bf16
  ushort_t* vW2p  = W2p + 262144;                    // 65536 bf16
  ushort_t* WveFp = vW2p + 65536;                    // 4096 bf16
  ushort_t* v0gh  = WveFp + 4096;                    // 131072 bf16
  ushort_t* hn_ws = v0gh + 131072;                   // 4194304 bf16 (8 MB)
  float* out = (float*)d_out;

  eca_pre<<<dim3(1282), dim3(256), 0, stream>>>(
      mW1, mW2, vW2, Wve, vW1, bve, vb1,
      a, Wk, bk, Wv, bv, Wq, bq, Wqe, bqe,
      mg, mbn, mb2,
      W1p, W2p, vW2p, WveFp, bveF, cm1, cm2, v0gh, kqf, bqkg);
  eca_front<<<dim3(NB * NC), dim3(512), 0, stream>>>(
      inputs, p, Bq, Bv, vg, vbn, kqf, bqkg, WveFp, bveF, attw, hn_ws);
  eca_gemm<<<dim3(NB * NC), dim3(512), 0, stream>>>(
      hn_ws, attw, v0gh, vb2, mb1, W1p, vW2p, A_ws, S1w);
  eca_y<<<dim3(256), dim3(256), 0, stream>>>(A_ws, W2p, S1w, cm1, cm2, mg, yws);
  eca_out<<<dim3(128), dim3(256), 0, stream>>>(yws, Wo, bo, out);
}

// Round 17
// 216.078 us; speedup vs baseline: 1.1490x; 1.0063x over previous
//
#include <hip/hip_runtime.h>
#include <hip/hip_bf16.h>
#include <math.h>

#define NB 2
#define NC 256
#define NZ 128
#define NHEADS 8
#define HDIM 64
#define HHID 512
#define EPSF 1e-5f

typedef __attribute__((ext_vector_type(8))) short bf16x8;
typedef __attribute__((ext_vector_type(4))) float f32x4;
typedef unsigned short ushort_t;

__device__ __forceinline__ float gelu_f(float x){
  const float u = 0.7978845608028654f * (x + 0.044715f * x * x * x);
  const float t = 1.0f - 2.0f / (__expf(2.0f * u) + 1.0f);  // tanh(u)
  return 0.5f * x * (1.0f + t);
}

__device__ __forceinline__ ushort_t f2bf(float x){
  unsigned int u = __float_as_uint(x);
  unsigned int r = ((u >> 16) & 1u) + 0x7fffu;   // round-to-nearest-even
  return (ushort_t)((u + r) >> 16);
}

__device__ __forceinline__ float bf2f(ushort_t u){
  return __uint_as_float(((unsigned int)u) << 16);
}

// sin(2*pi*t), cos(2*pi*t): v_sin/v_cos take REVOLUTIONS, fract-reduce first.
__device__ __forceinline__ void fsincos(float t, float* sn, float* cn){
  const float fr = t - floorf(t);
  *sn = __builtin_amdgcn_sinf(fr);
  *cn = __builtin_amdgcn_cosf(fr);
}

// sin(2*pi*t) only (cos obtained by caller via t+0.25)
__device__ __forceinline__ float fsin1(float t){
  const float fr = t - floorf(t);
  return __builtin_amdgcn_sinf(fr);
}

// ---------------- K0: pack weights + cm folds + per-(b,z) prep ----------------
// B-frag: idx=((s*T + t)*64 + L)*8 + j  <->  W[k=s*32+8*(L>>4)+j][n=16*t+(L&15)]
__global__ __launch_bounds__(256) void eca_pre(
    const float* __restrict__ mW1, const float* __restrict__ mW2, const float* __restrict__ vW2,
    const float* __restrict__ Wve, const float* __restrict__ vW1,
    const float* __restrict__ bve, const float* __restrict__ vb1,
    const float* __restrict__ a, const float* __restrict__ Wk, const float* __restrict__ bk,
    const float* __restrict__ Wv, const float* __restrict__ bv,
    const float* __restrict__ Wq, const float* __restrict__ bq,
    const float* __restrict__ Wqe, const float* __restrict__ bqe,
    const float* __restrict__ mg, const float* __restrict__ mbn, const float* __restrict__ mb2,
    ushort_t* __restrict__ W1p, ushort_t* __restrict__ W2p, ushort_t* __restrict__ vW2p,
    ushort_t* __restrict__ WveFp, float* __restrict__ bveF,
    float* __restrict__ cm1, float* __restrict__ cm2,
    ushort_t* __restrict__ v0gh, float* __restrict__ kqf, float* __restrict__ bqkg)
{
  const int bx = blockIdx.x;
  const int tid = threadIdx.x;
  __shared__ float s_wf[64][64];
  __shared__ float s_a[64];
  __shared__ float s_k[512];
  __shared__ float s_kq[512];

  if (bx < 1024){
    const int i = bx * 256 + tid;
    {
      const int j = i & 7, L = (i >> 3) & 63, t = (i >> 9) & 31, s = i >> 14;
      const int k = s * 32 + ((L >> 4) << 3) + j;
      const int n = (t << 4) + (L & 15);
      W1p[i] = f2bf(mW1[k * 512 + n]);
      W2p[i] = f2bf(mW2[k * 512 + n]);
    }
    if (i < 65536){
      const int j = i & 7, L = (i >> 3) & 63, gb = (i >> 9) & 1, tp = (i >> 10) & 31, s = i >> 15;
      const int k = s * 32 + ((L >> 4) << 3) + j;
      const int n = (tp << 4) + (L & 15) + gb * 512;
      vW2p[i] = f2bf(vW2[k * 1024 + n]);
    }
    return;
  }
  if (bx == 1024){
    // fused front weight: WveF = Wve @ vW1 (64x64), bveF = bve@vW1 + vb1
    const int m = tid >> 2, iq = tid & 3;
    float accv[16];
    #pragma unroll
    for (int ii = 0; ii < 16; ++ii) accv[ii] = 0.f;
    for (int k = 0; k < 64; ++k){
      const float wv = Wve[m * 64 + k];
      const float4* vr = (const float4*)(vW1 + k * 64 + iq * 16);
      float t4[16];
      *(float4*)&t4[0] = vr[0]; *(float4*)&t4[4] = vr[1];
      *(float4*)&t4[8] = vr[2]; *(float4*)&t4[12] = vr[3];
      #pragma unroll
      for (int ii = 0; ii < 16; ++ii) accv[ii] += wv * t4[ii];
    }
    #pragma unroll
    for (int ii = 0; ii < 16; ++ii) s_wf[m][iq * 16 + ii] = accv[ii];
    if (tid < 64){
      float acc = vb1[tid];
      for (int k = 0; k < 64; ++k) acc += bve[k] * vW1[k * 64 + tid];
      bveF[tid] = acc;
    }
    __syncthreads();
    for (int e = tid; e < 4096; e += 256){
      const int j = e & 7, L = (e >> 3) & 63, t = (e >> 9) & 3, s = e >> 11;
      const int k = s * 32 + ((L >> 4) << 3) + j;
      const int n = (t << 4) + (L & 15);
      WveFp[e] = f2bf(s_wf[k][n]);
    }
    return;
  }
  if (bx == 1025){
    // cm1[n] = sum_k mg[k]*mW2[k,n]; cm2[n] = sum_k mbn[k]*mW2[k,n] + mb2[n]
    for (int nn = tid; nn < 512; nn += 256){
      float c1 = 0.f, c2 = 0.f;
      for (int k = 0; k < 512; ++k){
        const float w2 = mW2[k * 512 + nn];
        c1 += mg[k] * w2;
        c2 += mbn[k] * w2;
      }
      cm1[nn] = c1;
      cm2[nn] = c2 + mb2[nn];
    }
    return;
  }

  // ---- prep: bz = bx - 1026 ----
  const int bz = bx - 1026;
  if (tid < 64) s_a[tid] = a[bz * 64 + tid];
  __syncthreads();
  #pragma unroll
  for (int jo = 0; jo < 2; ++jo){
    const int j = tid + jo * 256;
    float accK = bk[j], accV = bv[j];
    for (int i = 0; i < 64; ++i){
      const float av = s_a[i];
      accK += av * Wk[i * 512 + j];
      accV += av * Wv[i * 512 + j];
    }
    s_k[j] = accK;
    v0gh[(size_t)bz * 512 + j] = f2bf(accV);
  }
  __syncthreads();
  #pragma unroll
  for (int io = 0; io < 2; ++io){
    const int idx = tid + io * 256;
    const int h = idx >> 6, i = idx & 63;
    float acc = 0.f;
    for (int j = 0; j < 64; ++j)
      acc += Wq[i * 512 + h * 64 + j] * s_k[h * 64 + j];
    s_kq[idx] = acc;
  }
  __syncthreads();
  // KqF[m,h]; layout kqf[bz*512 + (m>>4)*128 + h*16 + (m&15)]
  #pragma unroll
  for (int io = 0; io < 2; ++io){
    const int idx = tid + io * 256;
    const int m = idx >> 3, h = idx & 7;
    float acc = 0.f;
    for (int i = 0; i < 64; ++i) acc += Wqe[m * 64 + i] * s_kq[h * 64 + i];
    kqf[(size_t)bz * 512 + (m >> 4) * 128 + h * 16 + (m & 15)] = acc;
  }
  if (tid < 8){
    float acc = 0.f;
    for (int j = 0; j < 64; ++j) acc += bq[tid * 64 + j] * s_k[tid * 64 + j];
    for (int i = 0; i < 64; ++i) acc += bqe[i] * s_kq[tid * 64 + i];
    bqkg[bz * 8 + tid] = acc;
  }
}

// ---------------- K2: per-(b,c) logits+softmax+front -> attw + hn frags ----------------
__global__ __launch_bounds__(512, 4) void eca_front(
    const float* __restrict__ inputs, const float* __restrict__ p,
    const float* __restrict__ Bq, const float* __restrict__ Bv,
    const float* __restrict__ vg, const float* __restrict__ vbn,
    const float* __restrict__ kqf, const float* __restrict__ bqkg,
    const ushort_t* __restrict__ WveFp, const float* __restrict__ bveF,
    float* __restrict__ attw, ushort_t* __restrict__ hn_ws)
{
  const int bc = blockIdx.x;
  const int b = bc >> 8;
  const int tid = threadIdx.x;
  const int w = tid >> 6, L = tid & 63;
  const int al = L & 15, g = L >> 4;
  const int bz0 = b * NZ;

  __shared__ __align__(16) ushort_t s_HN[4096];  // 8KB hn frags (one pass)
  __shared__ float s_att[1024];
  __shared__ float s_u[512];
  __shared__ float s_qpt[3];

  if (tid < 3) s_qpt[tid] = inputs[bc * 3 + tid];
  __syncthreads();

  // ---------- logits: thread (z = tid>>2, q = tid&3); two 4-head groups ----------
  // q<2 threads need sin, q>=2 need cos = sin(t + 1/4 rev): fold phase, ONE v_sin per mi.
  {
    const int z = tid >> 2, q = tid & 3;
    const float qoff = (q < 2) ? 0.f : 0.25f;
    const float iv0 = s_qpt[0] - p[(bz0 + z) * 3 + 0];
    const float iv1 = s_qpt[1] - p[(bz0 + z) * 3 + 1];
    const float iv2 = s_qpt[2] - p[(bz0 + z) * 3 + 2];
    float tr[16];
    #pragma unroll
    for (int mi = 0; mi < 16; ++mi){
      const int mb = (q & 1) * 16 + mi;
      const float d = iv0 * Bq[mb] + iv1 * Bq[32 + mb] + iv2 * Bq[64 + mb] + qoff;
      tr[mi] = fsin1(d);
    }
    const float* kfb = kqf + (size_t)(bz0 + z) * 512 + q * 128;
    #pragma unroll 1
    for (int hg = 0; hg < 2; ++hg){
      float lg[4];
      #pragma unroll
      for (int h4 = 0; h4 < 4; ++h4){
        const int h = hg * 4 + h4;
        const float4 k0 = *(const float4*)(kfb + h * 16);
        const float4 k1 = *(const float4*)(kfb + h * 16 + 4);
        const float4 k2 = *(const float4*)(kfb + h * 16 + 8);
        const float4 k3 = *(const float4*)(kfb + h * 16 + 12);
        lg[h4] = tr[0]*k0.x + tr[1]*k0.y + tr[2]*k0.z + tr[3]*k0.w
               + tr[4]*k1.x + tr[5]*k1.y + tr[6]*k1.z + tr[7]*k1.w
               + tr[8]*k2.x + tr[9]*k2.y + tr[10]*k2.z + tr[11]*k2.w
               + tr[12]*k3.x + tr[13]*k3.y + tr[14]*k3.z + tr[15]*k3.w;
      }
      #pragma unroll
      for (int h4 = 0; h4 < 4; ++h4){
        lg[h4] += __shfl_xor(lg[h4], 1);
        lg[h4] += __shfl_xor(lg[h4], 2);
      }
      const int h = hg * 4 + q;
      s_att[h * 128 + z] = (lg[q] + bqkg[(bz0 + z) * 8 + h]) * 0.125f;
    }
  }
  __syncthreads();

  // ---------- softmax over z (head w per wave) -> attw ----------
  {
    const float x0 = s_att[w * 128 + L], x1 = s_att[w * 128 + L + 64];
    float mx = fmaxf(x0, x1);
    #pragma unroll
    for (int off = 32; off; off >>= 1) mx = fmaxf(mx, __shfl_xor(mx, off));
    const float e0 = __expf(x0 - mx), e1 = __expf(x1 - mx);
    float sm = e0 + e1;
    #pragma unroll
    for (int off = 32; off; off >>= 1) sm += __shfl_xor(sm, off);
    const float inv = 1.f / sm;
    attw[(size_t)bc * 1024 + w * 128 + L]      = e0 * inv;
    attw[(size_t)bc * 1024 + w * 128 + L + 64] = e1 * inv;
  }

  const int rtf = w & 3, ch2 = w >> 2;

  #pragma unroll 1
  for (int pass = 0; pass < 2; ++pass){
    const int zp = pass * 64;
    __syncthreads();                                   // protect s_u / s_HN reuse

    // ---------- front: hn = LN64(gelu(f @ WveF + bveF)) ----------
    {
      const int zz = bz0 + zp + rtf * 16 + al;
      const float iv0 = s_qpt[0] - p[zz * 3 + 0];
      const float iv1 = s_qpt[1] - p[zz * 3 + 1];
      const float iv2 = s_qpt[2] - p[zz * 3 + 2];
      bf16x8 fa0, fa1;
      #pragma unroll
      for (int j = 0; j < 8; ++j){
        const int m = g * 8 + j;
        const float d = iv0 * Bv[m] + iv1 * Bv[32 + m] + iv2 * Bv[64 + m];
        float sn, cn; fsincos(d, &sn, &cn);
        fa0[j] = (short)f2bf(sn);
        fa1[j] = (short)f2bf(cn);
      }
      f32x4 accf[2] = {{0,0,0,0},{0,0,0,0}};
      #pragma unroll
      for (int ct = 0; ct < 2; ++ct){
        const int t = ch2 * 2 + ct;
        const bf16x8 b0 = *(const bf16x8*)(WveFp + ((0 * 4 + t) * 64 + L) * 8);
        const bf16x8 b1 = *(const bf16x8*)(WveFp + ((1 * 4 + t) * 64 + L) * 8);
        accf[ct] = __builtin_amdgcn_mfma_f32_16x16x32_bf16(fa0, b0, accf[ct], 0, 0, 0);
        accf[ct] = __builtin_amdgcn_mfma_f32_16x16x32_bf16(fa1, b1, accf[ct], 0, 0, 0);
      }
      float h1v[2][4];
      #pragma unroll
      for (int r = 0; r < 4; ++r){
        float sv = 0.f, qv = 0.f;
        #pragma unroll
        for (int ct = 0; ct < 2; ++ct){
          const float v = gelu_f(accf[ct][r] + bveF[ch2 * 32 + ct * 16 + al]);
          h1v[ct][r] = v; sv += v; qv += v * v;
        }
        sv += __shfl_xor(sv, 1); sv += __shfl_xor(sv, 2);
        sv += __shfl_xor(sv, 4); sv += __shfl_xor(sv, 8);
        qv += __shfl_xor(qv, 1); qv += __shfl_xor(qv, 2);
        qv += __shfl_xor(qv, 4); qv += __shfl_xor(qv, 8);
        if (al == 0){
          const int row = rtf * 16 + 4 * g + r;
          s_u[row * 4 + ch2 * 2 + 0] = sv;
          s_u[row * 4 + ch2 * 2 + 1] = qv;
        }
      }
      __syncthreads();
      #pragma unroll
      for (int r = 0; r < 4; ++r){
        const int row = rtf * 16 + 4 * g + r;
        const float sv = s_u[row * 4 + 0] + s_u[row * 4 + 2];
        const float qv = s_u[row * 4 + 1] + s_u[row * 4 + 3];
        const float mu = sv * (1.f / 64.f);
        const float rs = rsqrtf(qv * (1.f / 64.f) - mu * mu + EPSF);
        #pragma unroll
        for (int ct = 0; ct < 2; ++ct){
          const int n = ch2 * 32 + ct * 16 + al;
          const float val = (h1v[ct][r] - mu) * rs * vg[n] + vbn[n];
          s_HN[((n >> 5) * 4 + rtf) * 512 + ((4 * g + r) + 16 * ((n >> 3) & 3)) * 8 + (n & 7)] = f2bf(val);
        }
      }
    }
    __syncthreads();
    // copy hn frags to ws (linear, vectorized)
    ((uint4*)(hn_ws + (size_t)bc * 8192 + pass * 4096))[tid] = ((const uint4*)s_HN)[tid];
  }
}

// ---------------- K3: per-(b,c) gb + GEMM1 + A' via MFMA (slim arch-VGPR peaks) ----------------
// A_ws[h][bc][k] (f32) = sum_z att[h,z]*rs[z]*h2[z,k]; S1_ws[bc][h] = sum_z att*mu*rs
__global__ __launch_bounds__(512, 4) void eca_gemm(
    const ushort_t* __restrict__ hn_ws, const float* __restrict__ attw,
    const ushort_t* __restrict__ v0gh,
    const float* __restrict__ vb2, const float* __restrict__ mb1,
    const ushort_t* __restrict__ W1p, const ushort_t* __restrict__ vW2p,
    float* __restrict__ A_ws, float* __restrict__ S1_ws)
{
  const int bc = blockIdx.x;
  const int b = bc >> 8;
  const int tid = threadIdx.x;
  const int w = tid >> 6, L = tid & 63;
  const int al = L & 15, g = L >> 4;
  const int bz0 = b * NZ;

  __shared__ __align__(16) ushort_t s_A[16 * 4 * 64 * 8];   // 64KB
  __shared__ __align__(16) ushort_t s_HN[4096];             // 8KB
  __shared__ float s_att[1024];
  __shared__ float s_u[512];
  __shared__ float s_rs[32];
  __shared__ float s_rsmu[128];

  s_att[tid] = attw[(size_t)bc * 1024 + tid];
  s_att[tid + 512] = attw[(size_t)bc * 1024 + 512 + tid];

  f32x4 accA[4];
  #pragma unroll
  for (int ct = 0; ct < 4; ++ct) accA[ct] = (f32x4){0.f, 0.f, 0.f, 0.f};

  #pragma unroll 1
  for (int pass = 0; pass < 2; ++pass){
    const int zp = pass * 64;
    __syncthreads();
    // stage hn frags (8KB)
    {
      const uint4 v = ((const uint4*)(hn_ws + (size_t)bc * 8192 + pass * 4096))[tid];
      ((uint4*)s_HN)[tid] = v;
    }
    __syncthreads();

    // ---------- gb MFMA: per-rt epilogue-inline (low arch live; vW2p re-read per rt) ----------
    #pragma unroll 1
    for (int it = 0; it < 4; ++it){
      const int tp = w * 4 + it;
      const int n = tp * 16 + al;
      const float gbias = vb2[n], bbias = vb2[512 + n];
      #pragma unroll 1
      for (int rt = 0; rt < 4; ++rt){
        f32x4 accg = {0,0,0,0}, accb = {0,0,0,0};
        #pragma unroll
        for (int s = 0; s < 2; ++s){
          const bf16x8 bg = *(const bf16x8*)(vW2p + (size_t)(((s * 32 + tp) * 2 + 0) * 64 + L) * 8);
          const bf16x8 bb = *(const bf16x8*)(vW2p + (size_t)(((s * 32 + tp) * 2 + 1) * 64 + L) * 8);
          const bf16x8 af = *(const bf16x8*)(s_HN + ((s * 4 + rt) * 64 + L) * 8);
          accg = __builtin_amdgcn_mfma_f32_16x16x32_bf16(af, bg, accg, 0, 0, 0);
          accb = __builtin_amdgcn_mfma_f32_16x16x32_bf16(af, bb, accb, 0, 0, 0);
        }
        #pragma unroll
        for (int r = 0; r < 4; ++r){
          const int zl = rt * 16 + 4 * g + r;
          const float v0v = bf2f(v0gh[(size_t)(bz0 + zp + zl) * 512 + n]);
          const float vf = v0v * (1.f + accg[r] + gbias) + (accb[r] + bbias);
          s_A[((n >> 5) * 4 + rt) * 512 + ((4 * g + r) + 16 * ((n >> 3) & 3)) * 8 + (n & 7)] = f2bf(vf);
        }
      }
    }
    __syncthreads();

    // ---------- GEMM1 (two 32-z chunks, ct-split halves): h2; stats via LDS; A' via MFMA ----------
    #pragma unroll 1
    for (int rc = 0; rc < 2; ++rc){
      // half A: ct 0,1
      f32x4 accP[2][2];
      #pragma unroll
      for (int i = 0; i < 2; ++i){ accP[i][0] = (f32x4){0,0,0,0}; accP[i][1] = (f32x4){0,0,0,0}; }
      #pragma unroll 1
      for (int s = 0; s < 16; ++s){
        bf16x8 bw0 = *(const bf16x8*)(W1p + (size_t)((s * 32 + w * 4 + 0) * 64 + L) * 8);
        bf16x8 bw1 = *(const bf16x8*)(W1p + (size_t)((s * 32 + w * 4 + 1) * 64 + L) * 8);
        const bf16x8 a0 = *(const bf16x8*)(s_A + ((s * 4 + rc * 2 + 0) * 64 + L) * 8);
        const bf16x8 a1 = *(const bf16x8*)(s_A + ((s * 4 + rc * 2 + 1) * 64 + L) * 8);
        accP[0][0] = __builtin_amdgcn_mfma_f32_16x16x32_bf16(a0, bw0, accP[0][0], 0, 0, 0);
        accP[0][1] = __builtin_amdgcn_mfma_f32_16x16x32_bf16(a0, bw1, accP[0][1], 0, 0, 0);
        accP[1][0] = __builtin_amdgcn_mfma_f32_16x16x32_bf16(a1, bw0, accP[1][0], 0, 0, 0);
        accP[1][1] = __builtin_amdgcn_mfma_f32_16x16x32_bf16(a1, bw1, accP[1][1], 0, 0, 0);
      }
      // gelu half A + stats partials -> s_u
      #pragma unroll
      for (int i = 0; i < 2; ++i){
        #pragma unroll
        for (int r = 0; r < 4; ++r){
          float sv = 0.f, qv = 0.f;
          #pragma unroll
          for (int ct = 0; ct < 2; ++ct){
            const float v = gelu_f(accP[i][ct][r] + mb1[w * 64 + ct * 16 + al]);
            accP[i][ct][r] = v; sv += v; qv += v * v;
          }
          sv += __shfl_xor(sv, 1); sv += __shfl_xor(sv, 2);
          sv += __shfl_xor(sv, 4); sv += __shfl_xor(sv, 8);
          qv += __shfl_xor(qv, 1); qv += __shfl_xor(qv, 2);
          qv += __shfl_xor(qv, 4); qv += __shfl_xor(qv, 8);
          if (al == 0){
            const int zloc = i * 16 + 4 * g + r;
            s_u[zloc * 16 + w * 2 + 0] = sv;
            s_u[zloc * 16 + w * 2 + 1] = qv;
          }
        }
      }
      // half B: ct 2,3
      f32x4 accQ[2][2];
      #pragma unroll
      for (int i = 0; i < 2; ++i){ accQ[i][0] = (f32x4){0,0,0,0}; accQ[i][1] = (f32x4){0,0,0,0}; }
      #pragma unroll 1
      for (int s = 0; s < 16; ++s){
        bf16x8 bw0 = *(const bf16x8*)(W1p + (size_t)((s * 32 + w * 4 + 2) * 64 + L) * 8);
        bf16x8 bw1 = *(const bf16x8*)(W1p + (size_t)((s * 32 + w * 4 + 3) * 64 + L) * 8);
        const bf16x8 a0 = *(const bf16x8*)(s_A + ((s * 4 + rc * 2 + 0) * 64 + L) * 8);
        const bf16x8 a1 = *(const bf16x8*)(s_A + ((s * 4 + rc * 2 + 1) * 64 + L) * 8);
        accQ[0][0] = __builtin_amdgcn_mfma_f32_16x16x32_bf16(a0, bw0, accQ[0][0], 0, 0, 0);
        accQ[0][1] = __builtin_amdgcn_mfma_f32_16x16x32_bf16(a0, bw1, accQ[0][1], 0, 0, 0);
        accQ[1][0] = __builtin_amdgcn_mfma_f32_16x16x32_bf16(a1, bw0, accQ[1][0], 0, 0, 0);
        accQ[1][1] = __builtin_amdgcn_mfma_f32_16x16x32_bf16(a1, bw1, accQ[1][1], 0, 0, 0);
      }
      // gelu half B + stats add into s_u (single writer lane per row)
      #pragma unroll
      for (int i = 0; i < 2; ++i){
        #pragma unroll
        for (int r = 0; r < 4; ++r){
          float sv = 0.f, qv = 0.f;
          #pragma unroll
          for (int ct = 0; ct < 2; ++ct){
            const float v = gelu_f(accQ[i][ct][r] + mb1[w * 64 + (ct + 2) * 16 + al]);
            accQ[i][ct][r] = v; sv += v; qv += v * v;
          }
          sv += __shfl_xor(sv, 1); sv += __shfl_xor(sv, 2);
          sv += __shfl_xor(sv, 4); sv += __shfl_xor(sv, 8);
          qv += __shfl_xor(qv, 1); qv += __shfl_xor(qv, 2);
          qv += __shfl_xor(qv, 4); qv += __shfl_xor(qv, 8);
          if (al == 0){
            const int zloc = i * 16 + 4 * g + r;
            s_u[zloc * 16 + w * 2 + 0] += sv;
            s_u[zloc * 16 + w * 2 + 1] += qv;
          }
        }
      }
      __syncthreads();                 // waves done reading chunk's A-frags + partials visible
      if (tid < 32){
        float sv = 0.f, qv = 0.f;
        #pragma unroll
        for (int ww = 0; ww < 8; ++ww){ sv += s_u[tid * 16 + ww * 2]; qv += s_u[tid * 16 + ww * 2 + 1]; }
        const float mu = sv * (1.f / 512.f);
        const float rs = rsqrtf(qv * (1.f / 512.f) - mu * mu + EPSF);
        s_rs[tid] = rs;
        s_rsmu[zp + rc * 32 + tid] = mu * rs;
      }
      __syncthreads();
      // write h2*rs as B-frags (K=z) into this chunk's now-dead s_A slots
      #pragma unroll
      for (int i = 0; i < 2; ++i){
        #pragma unroll
        for (int r = 0; r < 4; ++r){
          const int zr = i * 16 + 4 * g + r;         // chunk-local z 0..31
          const float rsv = s_rs[zr];
          #pragma unroll
          for (int ct = 0; ct < 4; ++ct){
            const int sl = 2 * w + (ct >> 1);
            const int rt = rc * 2 + (ct & 1);
            const float hv = (ct < 2) ? accP[i][ct][r] : accQ[i][ct - 2][r];
            s_A[((sl * 4 + rt) * 64 + (zr >> 3) * 16 + al) * 8 + (zr & 7)] = f2bf(hv * rsv);
          }
        }
      }
      __syncthreads();
      // A' MFMA: accA[ct] += att_frag @ (rs*h2)_frag  (K = 32 z of this chunk)
      {
        const int chunk = pass * 2 + rc;
        bf16x8 fa;
        if (al < 8){
          const float* ar = s_att + al * 128 + chunk * 32 + g * 8;
          #pragma unroll
          for (int j = 0; j < 8; ++j) fa[j] = (short)f2bf(ar[j]);
        } else {
          #pragma unroll
          for (int j = 0; j < 8; ++j) fa[j] = 0;
        }
        #pragma unroll
        for (int ct = 0; ct < 4; ++ct){
          const int sl = 2 * w + (ct >> 1);
          const int rt = rc * 2 + (ct & 1);
          const bf16x8 bb = *(const bf16x8*)(s_A + ((sl * 4 + rt) * 64 + L) * 8);
          accA[ct] = __builtin_amdgcn_mfma_f32_16x16x32_bf16(fa, bb, accA[ct], 0, 0, 0);
        }
      }
    }
  }

  // ---------- S1[h] = sum_z att[h,z]*rsmu[z] (wave w -> head w) ----------
  __syncthreads();
  {
    float sS = s_att[w * 128 + L] * s_rsmu[L] + s_att[w * 128 + L + 64] * s_rsmu[L + 64];
    #pragma unroll
    for (int off = 32; off; off >>= 1) sS += __shfl_xor(sS, off);
    if (L == 0) S1_ws[bc * 8 + w] = sS;
  }

  // ---------- write A' (f32): lane rows h = g*4+r valid for g<2 ----------
  if (g < 2){
    #pragma unroll
    for (int ct = 0; ct < 4; ++ct){
      #pragma unroll
      for (int r = 0; r < 4; ++r){
        const int h = g * 4 + r;
        A_ws[((size_t)h * 512 + bc) * 512 + w * 64 + ct * 16 + al] = accA[ct][r];
      }
    }
  }
}

// ---------------- K4: y[c,n] = (mg*A'[h(n),c,:]) @ mW2[:,n] - S1[c,h]*cm1[n] + cm2[n] ----------------
__global__ __launch_bounds__(256) void eca_y(
    const float* __restrict__ A_ws, const ushort_t* __restrict__ W2p,
    const float* __restrict__ S1_ws,
    const float* __restrict__ cm1, const float* __restrict__ cm2,
    const float* __restrict__ mg,
    float* __restrict__ yws)
{
  const int bx = blockIdx.x;
  const int h = bx >> 5, ctile = bx & 31;
  const int c0 = ctile * 16;
  const int tid = threadIdx.x;
  const int w = tid >> 6, L = tid & 63;
  const int al = L & 15, g = L >> 4;
  __shared__ float s_S1[16];
  if (tid < 16) s_S1[tid] = S1_ws[(c0 + tid) * 8 + h];
  __syncthreads();
  f32x4 acc = {0.f, 0.f, 0.f, 0.f};
  const int t = h * 4 + w;
  const float* Arow = A_ws + ((size_t)h * 512 + c0 + al) * 512;
  #pragma unroll 1
  for (int s = 0; s < 16; ++s){
    const int k0 = s * 32 + g * 8;
    const float4 a0 = *(const float4*)(Arow + k0);
    const float4 a1 = *(const float4*)(Arow + k0 + 4);
    const float4 m0 = *(const float4*)(mg + k0);
    const float4 m1 = *(const float4*)(mg + k0 + 4);
    bf16x8 a;
    a[0] = (short)f2bf(a0.x * m0.x); a[1] = (short)f2bf(a0.y * m0.y);
    a[2] = (short)f2bf(a0.z * m0.z); a[3] = (short)f2bf(a0.w * m0.w);
    a[4] = (short)f2bf(a1.x * m1.x); a[5] = (short)f2bf(a1.y * m1.y);
    a[6] = (short)f2bf(a1.z * m1.z); a[7] = (short)f2bf(a1.w * m1.w);
    const bf16x8 bw = *(const bf16x8*)(W2p + (size_t)((s * 32 + t) * 64 + L) * 8);
    acc = __builtin_amdgcn_mfma_f32_16x16x32_bf16(a, bw, acc, 0, 0, 0);
  }
  const int n = h * 64 + w * 16 + al;
  const float c1 = cm1[n], c2 = cm2[n];
  #pragma unroll
  for (int r = 0; r < 4; ++r){
    const int c = c0 + 4 * g + r;
    yws[(size_t)c * 512 + n] = acc[r] - s_S1[4 * g + r] * c1 + c2;
  }
}

// ---------------- K5: out = y @ Wo + bo (f32) ----------------
__global__ __launch_bounds__(256) void eca_out(
    const float* __restrict__ y, const float* __restrict__ Wo, const float* __restrict__ bo,
    float* __restrict__ out)
{
  const int rt = blockIdx.x >> 2, ct = blockIdx.x & 3;    // 32 row-tiles x 4 col-tiles
  const int tid = threadIdx.x;
  __shared__ float s_y[16][512];
  const float* yb = y + (size_t)rt * 16 * 512;
  for (int i = tid; i < 16 * 128; i += 256)
    ((float4*)&s_y[0][0])[i] = ((const float4*)yb)[i];
  __syncthreads();
  const int jc = ct * 128 + (tid & 31) * 4;
  const int r0 = (tid >> 5) * 2;
  float acc[2][4] = {};
  #pragma unroll 4
  for (int k = 0; k < 512; ++k){
    const float4 wv = *(const float4*)(Wo + (size_t)k * 512 + jc);
    #pragma unroll
    for (int r = 0; r < 2; ++r){
      const float yvv = s_y[r0 + r][k];
      acc[r][0] += yvv * wv.x; acc[r][1] += yvv * wv.y;
      acc[r][2] += yvv * wv.z; acc[r][3] += yvv * wv.w;
    }
  }
  const float4 bv4 = *(const float4*)(bo + jc);
  #pragma unroll
  for (int r = 0; r < 2; ++r){
    float4 o;
    o.x = acc[r][0] + bv4.x; o.y = acc[r][1] + bv4.y;
    o.z = acc[r][2] + bv4.z; o.w = acc[r][3] + bv4.w;
    *(float4*)(out + (size_t)(rt * 16 + r0 + r) * 512 + jc) = o;
  }
}

extern "C" void kernel_launch(void* const* d_in, const int* in_sizes, int n_in,
                              void* d_out, int out_size, void* d_ws, size_t ws_size,
                              hipStream_t stream)
{
  const float* inputs = (const float*)d_in[0];
  const float* p   = (const float*)d_in[1];
  const float* a   = (const float*)d_in[2];
  const float* Bq  = (const float*)d_in[3];
  const float* Wqe = (const float*)d_in[4];
  const float* bqe = (const float*)d_in[5];
  const float* Bv  = (const float*)d_in[6];
  const float* Wve = (const float*)d_in[7];
  const float* bve = (const float*)d_in[8];
  const float* Wq  = (const float*)d_in[9];
  const float* bq  = (const float*)d_in[10];
  const float* Wk  = (const float*)d_in[11];
  const float* bk  = (const float*)d_in[12];
  const float* Wv  = (const float*)d_in[13];
  const float* bv  = (const float*)d_in[14];
  const float* vW1 = (const float*)d_in[15];
  const float* vb1 = (const float*)d_in[16];
  const float* vg  = (const float*)d_in[17];
  const float* vbn = (const float*)d_in[18];
  const float* vW2 = (const float*)d_in[19];
  const float* vb2 = (const float*)d_in[20];
  const float* mW1 = (const float*)d_in[21];
  const float* mb1 = (const float*)d_in[22];
  const float* mg  = (const float*)d_in[23];
  const float* mbn = (const float*)d_in[24];
  const float* mW2 = (const float*)d_in[25];
  const float* mb2 = (const float*)d_in[26];
  const float* Wo  = (const float*)d_in[27];
  const float* bo  = (const float*)d_in[28];
  (void)in_sizes; (void)n_in; (void)out_size; (void)ws_size;

  float* kqf  = (float*)d_ws;                        // 131072 f32
  float* bqkg = kqf + 131072;                        // 2048 f32
  float* yws  = bqkg + 2048;                         // 262144 f32
  float* cm1  = yws + 262144;                        // 512 f32
  float* cm2  = cm1 + 512;                           // 512 f32
  float* S1w  = cm2 + 512;                           // 4096 f32
  float* attw = S1w + 4096;                          // 524288 f32 (2 MB)
  float* A_ws = attw + 524288;                       // 2097152 f32 (8 MB)
  float* bveF = A_ws + 2097152;                      // 64 f32
  ushort_t* W1p   = (ushort_t*)(bveF + 64);          // 262144 bf16
  ushort_t* W2p   = W1p + 262144;                    // 262144 bf16
  ushort_t* vW2p  = W2p + 262144;                    // 65536 bf16
  ushort_t* WveFp = vW2p + 65536;                    // 4096 bf16
  ushort_t* v0gh  = WveFp + 4096;                    // 131072 bf16
  ushort_t* hn_ws = v0gh + 131072;                   // 4194304 bf16 (8 MB)
  float* out = (float*)d_out;

  eca_pre<<<dim3(1282), dim3(256), 0, stream>>>(
      mW1, mW2, vW2, Wve, vW1, bve, vb1,
      a, Wk, bk, Wv, bv, Wq, bq, Wqe, bqe,
      mg, mbn, mb2,
      W1p, W2p, vW2p, WveFp, bveF, cm1, cm2, v0gh, kqf, bqkg);
  eca_front<<<dim3(NB * NC), dim3(512), 0, stream>>>(
      inputs, p, Bq, Bv, vg, vbn, kqf, bqkg, WveFp, bveF, attw, hn_ws);
  eca_gemm<<<dim3(NB * NC), dim3(512), 0, stream>>>(
      hn_ws, attw, v0gh, vb2, mb1, W1p, vW2p, A_ws, S1w);
  eca_y<<<dim3(256), dim3(256), 0, stream>>>(A_ws, W2p, S1w, cm1, cm2, mg, yws);
  eca_out<<<dim3(128), dim3(256), 0, stream>>>(yws, Wo, bo, out);
}